// Round 5
// baseline (468.999 us; speedup 1.0000x reference)
//
#include <hip/hip_runtime.h>
#include <math.h>

#define HW 4096
#define DIM 512

typedef __attribute__((ext_vector_type(8))) short short8;
typedef __attribute__((ext_vector_type(4))) float f32x4;

__device__ inline unsigned short f2bf(float f) {
    unsigned int u = __float_as_uint(f);
    u += 0x7fff + ((u >> 16) & 1);   // round-to-nearest-even
    return (unsigned short)(u >> 16);
}
__device__ inline float bf2f(unsigned short h) {
    return __uint_as_float(((unsigned int)h) << 16);
}
__device__ inline unsigned pack2(float a, float b) {
    return (unsigned)f2bf(a) | ((unsigned)f2bf(b) << 16);
}

// async global->LDS, 16 B per lane. LDS dest = wave-uniform base + lane*16.
__device__ inline void gld16(const void* g, void* lds) {
    __builtin_amdgcn_global_load_lds(
        (const __attribute__((address_space(1))) unsigned int*)g,
        (__attribute__((address_space(3))) unsigned int*)lds, 16, 0, 0);
}

// ---------- prep weights: bf16 w*g for q/k, fp32 w*g for v, bf16 w_out ------
__global__ void prep_weights(const float* __restrict__ w_q, const float* __restrict__ w_kv,
                             const float* __restrict__ w_out,
                             const float* __restrict__ ctx_g, const float* __restrict__ ctx_b,
                             const float* __restrict__ qs_g, const float* __restrict__ qs_b,
                             unsigned short* __restrict__ wq_b, unsigned short* __restrict__ wk_b,
                             unsigned short* __restrict__ wo_b, float* __restrict__ wv_g,
                             float* __restrict__ Avec, float* __restrict__ Cvec)
{
    int blk = blockIdx.x;
    int widx = blk >> 9;
    int o = blk & 511;
    int tid = threadIdx.x;
    const float *src, *g = nullptr, *beta = nullptr;
    if (widx == 0)      { src = w_q  + (size_t)o * DIM; g = qs_g;  beta = qs_b; }
    else if (widx == 1) { src = w_kv + (size_t)o * DIM; g = ctx_g; beta = ctx_b; }
    else if (widx == 2) { src = w_kv + (size_t)(512 + o) * DIM; g = ctx_g; beta = ctx_b; }
    else                { src = w_out + (size_t)o * DIM; }
    float a = 0.f, c = 0.f;
    for (int i = tid; i < DIM; i += 256) {
        float w = src[i];
        if (widx == 3) { wo_b[(size_t)o * DIM + i] = f2bf(w); continue; }
        float wg = w * g[i];
        if (widx == 0)      wq_b[(size_t)o * DIM + i] = f2bf(wg);
        else if (widx == 1) wk_b[(size_t)o * DIM + i] = f2bf(wg);
        else                wv_g[(size_t)o * DIM + i] = wg;
        a += wg; c += w * beta[i];
    }
    if (widx == 3) return;  // uniform across block
    __shared__ float sa[256], sc[256];
    sa[tid] = a; sc[tid] = c;
    __syncthreads();
    for (int s = 128; s > 0; s >>= 1) {
        if (tid < s) { sa[tid] += sa[tid + s]; sc[tid] += sc[tid + s]; }
        __syncthreads();
    }
    if (tid == 0) { Avec[widx * 512 + o] = sa[0]; Cvec[widx * 512 + o] = sc[0]; }
}

// ---------- fused fp32->bf16 transpose + chan stats, register-only ----------
// (R2 version: best measured 66-67 us. Read pattern is NOT the limiter --
// strided, streaming and swizzled variants all pin ~2 TB/s counted HBM.)
// Block: 32 pixels x 512 channels, grid (128, 8, 2). Thread owns 4 pixels x
// 8 consecutive channels (x2 halves): 16 float4 loads, in-register 4x8
// transpose -> 8 x uint4 stores (128 B-contiguous per 8-lane group).
// Stats: per-thread float4 partials -> shfl reduce -> 1 KB LDS combine.
__global__ __launch_bounds__(256) void conv_stats(
    const float* __restrict__ ctx, const float* __restrict__ qs,
    unsigned short* __restrict__ ctx_t, unsigned short* __restrict__ qs_t,
    float* __restrict__ ctx_m, float* __restrict__ ctx_r,
    float* __restrict__ qs_m, float* __restrict__ qs_r)
{
    int which = blockIdx.z;
    int b = blockIdx.y;
    int p0 = blockIdx.x * 32;
    const float* X = (which ? qs : ctx) + (size_t)b * DIM * HW;
    unsigned short* Xt = (which ? qs_t : ctx_t) + (size_t)b * HW * DIM;
    int tid = threadIdx.x;
    int pg = tid & 7;          // pixel group: 4 consecutive pixels
    int cR = tid >> 3;         // 0..31: channel row (8 consecutive channels)

    const float* src0 = X + p0 + pg * 4;

    float4 s4 = {0.f, 0.f, 0.f, 0.f};
    float4 q4 = {0.f, 0.f, 0.f, 0.f};
    float4 buf[2][8];

    // issue all 16 loads up-front for max memory-level parallelism
#pragma unroll
    for (int it = 0; it < 2; it++)
#pragma unroll
        for (int j = 0; j < 8; j++)
            buf[it][j] = *(const float4*)(src0 + (size_t)(it * 256 + cR * 8 + j) * HW);

#pragma unroll
    for (int it = 0; it < 2; it++) {
        unsigned short* dst = Xt + (size_t)(p0 + pg * 4) * 512 + it * 256 + cR * 8;
        uint4 o;
        // pixel r=0 (.x components)
        o.x = pack2(buf[it][0].x, buf[it][1].x);
        o.y = pack2(buf[it][2].x, buf[it][3].x);
        o.z = pack2(buf[it][4].x, buf[it][5].x);
        o.w = pack2(buf[it][6].x, buf[it][7].x);
        *(uint4*)(dst) = o;
        // pixel r=1 (.y)
        o.x = pack2(buf[it][0].y, buf[it][1].y);
        o.y = pack2(buf[it][2].y, buf[it][3].y);
        o.z = pack2(buf[it][4].y, buf[it][5].y);
        o.w = pack2(buf[it][6].y, buf[it][7].y);
        *(uint4*)(dst + 512) = o;
        // pixel r=2 (.z)
        o.x = pack2(buf[it][0].z, buf[it][1].z);
        o.y = pack2(buf[it][2].z, buf[it][3].z);
        o.z = pack2(buf[it][4].z, buf[it][5].z);
        o.w = pack2(buf[it][6].z, buf[it][7].z);
        *(uint4*)(dst + 1024) = o;
        // pixel r=3 (.w)
        o.x = pack2(buf[it][0].w, buf[it][1].w);
        o.y = pack2(buf[it][2].w, buf[it][3].w);
        o.z = pack2(buf[it][4].w, buf[it][5].w);
        o.w = pack2(buf[it][6].w, buf[it][7].w);
        *(uint4*)(dst + 1536) = o;
        // stats
#pragma unroll
        for (int j = 0; j < 8; j++) {
            float4 v = buf[it][j];
            s4.x += v.x; s4.y += v.y; s4.z += v.z; s4.w += v.w;
            q4.x = fmaf(v.x, v.x, q4.x);
            q4.y = fmaf(v.y, v.y, q4.y);
            q4.z = fmaf(v.z, v.z, q4.z);
            q4.w = fmaf(v.w, v.w, q4.w);
        }
    }

    // reduce over the 8 lanes sharing pg within the wave (covers 64 ch x 2)
#pragma unroll
    for (int off = 8; off <= 32; off <<= 1) {
        s4.x += __shfl_xor(s4.x, off, 64);
        s4.y += __shfl_xor(s4.y, off, 64);
        s4.z += __shfl_xor(s4.z, off, 64);
        s4.w += __shfl_xor(s4.w, off, 64);
        q4.x += __shfl_xor(q4.x, off, 64);
        q4.y += __shfl_xor(q4.y, off, 64);
        q4.z += __shfl_xor(q4.z, off, 64);
        q4.w += __shfl_xor(q4.w, off, 64);
    }

    __shared__ float sRed[4 * 32], qRed[4 * 32];
    int wave = tid >> 6, lane = tid & 63;
    if (lane < 8) {
        int base = wave * 32 + lane * 4;
        sRed[base + 0] = s4.x; sRed[base + 1] = s4.y;
        sRed[base + 2] = s4.z; sRed[base + 3] = s4.w;
        qRed[base + 0] = q4.x; qRed[base + 1] = q4.y;
        qRed[base + 2] = q4.z; qRed[base + 3] = q4.w;
    }
    __syncthreads();
    if (tid < 32) {
        float s = sRed[tid] + sRed[32 + tid] + sRed[64 + tid] + sRed[96 + tid];
        float q = qRed[tid] + qRed[32 + tid] + qRed[64 + tid] + qRed[96 + tid];
        float m = s * (1.0f / DIM);
        float var = q * (1.0f / DIM) - m * m;
        float r = 1.0f / sqrtf(var + 1e-5f);
        int pix = b * HW + p0 + tid;
        if (which == 0) { ctx_m[pix] = m; ctx_r[pix] = r; }
        else            { qs_m[pix]  = m; qs_r[pix]  = r; }
    }
}

// ---------- bf16 MFMA GEMM, 128x128 tile, BK=64, swizzled LDS ---------------
// K-loop: 8 steps of BK=64 (was 16 x BK=32): halves barrier count, 32 MFMA
// per wave between barrier pairs, staging pieces 128 B (was 64 B).
// LDS rows are 128 B -> XOR-swizzle (slot ^= row&7, 16 B slots) to avoid the
// 16-way ds_read_b128 bank conflict; staging pre-swizzles the GLOBAL source
// column so the LDS destination stays linear (global_load_lds requirement).
// MODE 0: q proj -> l2norm -> bf16 [p][512]; |.| row sums atomics into probe[b*512+m]
// MODE 1: k proj -> l2norm -> bf16 [p][512]; khs atomics into probe[(b*512+m)*64+h]
// MODE 2: out GEMM -> fp32 [m][p] with gamma*acc + LN(qsrc) residual
template<int MODE>
__global__ __launch_bounds__(256) void gemm_mfma(
    const unsigned short* __restrict__ Wb, const unsigned short* __restrict__ Xt,
    float* __restrict__ Y, unsigned short* __restrict__ Ybf,
    const float* __restrict__ mean, const float* __restrict__ rstd,
    const float* __restrict__ Arow, const float* __restrict__ Crow,
    float* __restrict__ probe,
    const float* __restrict__ qsrc, const float* __restrict__ g,
    const float* __restrict__ beta, const float* __restrict__ gammaPtr)
{
    int b = blockIdx.z;
    int n0 = blockIdx.x * 128;
    int m0 = blockIdx.y * 128;
    const unsigned short* Xb = Xt + (size_t)b * HW * DIM;
    __shared__ uint4 AsBuf[1024];   // 128 rows (m) x 64 k bf16 = 16 KB
    __shared__ uint4 BsBuf[1024];   // 128 rows (n) x 64 k bf16 = 16 KB
    unsigned short* As = (unsigned short*)AsBuf;
    unsigned short* Bs = (unsigned short*)BsBuf;
    int tid = threadIdx.x;
    int lane = tid & 63;
    int wave = tid >> 6;
    int wm = (wave >> 1) * 64;
    int wn = (wave & 1) * 64;
    int quad = lane >> 4;
    int l16 = lane & 15;

    // staging: round r covers rows r*32..+32; thread -> (row = tid>>3,
    // 16B slot = tid&7). LDS linear; global col pre-swizzled by row&7.
    int rr = tid >> 3;                    // 0..31
    int sw = ((tid & 7) ^ (rr & 7)) * 8;  // swizzled col (elems)
    int ldsW = tid & 192;                 // wave*64 uint4 (wave-uniform)
    const unsigned short* pA = Wb + (size_t)(m0 + rr) * DIM + sw;
    const unsigned short* pB = Xb + (size_t)(n0 + rr) * DIM + sw;

    // fragment-read swizzle: row&7 == l16&7 (wm, i*16 are multiples of 8)
    int fx = (l16 & 7) * 8;

    f32x4 acc[4][4];
#pragma unroll
    for (int i = 0; i < 4; i++)
#pragma unroll
        for (int j = 0; j < 4; j++) acc[i][j] = (f32x4){0.f, 0.f, 0.f, 0.f};

    for (int kt = 0; kt < 8; kt++) {
#pragma unroll
        for (int r = 0; r < 4; r++) {
            gld16(pA + (size_t)(r * 32) * DIM, AsBuf + r * 256 + ldsW);
            gld16(pB + (size_t)(r * 32) * DIM, BsBuf + r * 256 + ldsW);
        }
        pA += 64; pB += 64;
        __syncthreads();   // drains vmcnt -> staged data visible
#pragma unroll
        for (int t = 0; t < 2; t++) {
            short8 af[4], bfr[4];
#pragma unroll
            for (int i = 0; i < 4; i++)
                af[i] = *(const short8*)(As + (wm + i * 16 + l16) * 64 + ((t * 32 + quad * 8) ^ fx));
#pragma unroll
            for (int j = 0; j < 4; j++)
                bfr[j] = *(const short8*)(Bs + (wn + j * 16 + l16) * 64 + ((t * 32 + quad * 8) ^ fx));
#pragma unroll
            for (int i = 0; i < 4; i++)
#pragma unroll
                for (int j = 0; j < 4; j++)
                    acc[i][j] = __builtin_amdgcn_mfma_f32_16x16x32_bf16(af[i], bfr[j], acc[i][j], 0, 0, 0);
        }
        __syncthreads();
    }

    if (MODE < 2) {
        float pa[4][4] = {};
#pragma unroll
        for (int j = 0; j < 4; j++) {
            int n = n0 + wn + j * 16 + l16;
            int pix = b * HW + n;
            float mn = mean[pix], rs = rstd[pix];
            float y[4][4];
            float s2 = 0.f;
#pragma unroll
            for (int i = 0; i < 4; i++) {
                int mb = m0 + wm + i * 16 + quad * 4;
#pragma unroll
                for (int r = 0; r < 4; r++) {
                    float v = rs * (acc[i][j][r] - mn * Arow[mb + r]) + Crow[mb + r];
                    y[i][r] = v;
                    s2 = fmaf(v, v, s2);
                }
            }
            // head l2-norm: wave spans exactly one 64-channel head in m
            s2 += __shfl_xor(s2, 16, 64);
            s2 += __shfl_xor(s2, 32, 64);
            float inv = 1.0f / fmaxf(sqrtf(s2), 1e-12f);
            unsigned short* orow = Ybf + (size_t)(b * HW + n) * 512 + m0 + wm + quad * 4;
#pragma unroll
            for (int i = 0; i < 4; i++) {
                float v0 = y[i][0] * inv, v1 = y[i][1] * inv;
                float v2 = y[i][2] * inv, v3 = y[i][3] * inv;
                uint2 pk; pk.x = pack2(v0, v1); pk.y = pack2(v2, v3);
                *(uint2*)(orow + i * 16) = pk;
                pa[i][0] += fabsf(v0); pa[i][1] += fabsf(v1);
                pa[i][2] += fabsf(v2); pa[i][3] += fabsf(v3);
            }
        }
#pragma unroll
        for (int i = 0; i < 4; i++)
#pragma unroll
            for (int r = 0; r < 4; r++) {
                float v = pa[i][r];
                v += __shfl_xor(v, 1, 64);
                v += __shfl_xor(v, 2, 64);
                v += __shfl_xor(v, 4, 64);
                v += __shfl_xor(v, 8, 64);
                pa[i][r] = v;
            }
        if (l16 == 0) {
#pragma unroll
            for (int i = 0; i < 4; i++)
#pragma unroll
                for (int r = 0; r < 4; r++) {
                    int m = m0 + wm + i * 16 + quad * 4 + r;
                    if (MODE == 0) atomicAdd(&probe[b * 512 + m], pa[i][r]);
                    else atomicAdd(&probe[(size_t)(b * 512 + m) * 64 + ((n0 + wn) >> 6)], pa[i][r]);
                }
        }
    } else {
        float* Yb = Y + (size_t)b * DIM * HW;
        float gamma = gammaPtr[0];
        const float* qb = qsrc + (size_t)b * DIM * HW;
#pragma unroll
        for (int j = 0; j < 4; j++) {
            int n = n0 + wn + j * 16 + l16;
            int pix = b * HW + n;
            float mn = mean[pix], rs = rstd[pix];
#pragma unroll
            for (int i = 0; i < 4; i++) {
                int mb = m0 + wm + i * 16 + quad * 4;
#pragma unroll
                for (int r = 0; r < 4; r++) {
                    int m = mb + r;
                    float qn = (qb[(size_t)m * HW + n] - mn) * rs * g[m] + beta[m];
                    Yb[(size_t)m * HW + n] = gamma * acc[i][j][r] + qn;
                }
            }
        }
    }
}

// ---------- kws[(b*512+c)][w] = sum_h |k[b][h*64+w][c]|, vectorized ---------
__global__ __launch_bounds__(256) void kws_kernel(const unsigned short* __restrict__ kbf,
                                                  float* __restrict__ kws)
{
    int blk = blockIdx.x;     // b*64 + w
    int b = blk >> 6, w = blk & 63;
    int tid = threadIdx.x;
    int c8 = tid & 63;        // channel group of 8
    int hq = tid >> 6;        // 4 h-slices of 16
    float a[8] = {};
    for (int hh = 0; hh < 16; hh++) {
        const unsigned short* row = kbf + ((size_t)(b * HW + (hq * 16 + hh) * 64 + w)) * 512 + c8 * 8;
        uint4 pk = *(const uint4*)row;
        const unsigned short* u = (const unsigned short*)&pk;
#pragma unroll
        for (int j = 0; j < 8; j++) a[j] += fabsf(bf2f(u[j]));
    }
    __shared__ float red[512 * 4];
#pragma unroll
    for (int j = 0; j < 8; j++) red[(c8 * 8 + j) * 4 + hq] = a[j];
    __syncthreads();
    if (tid < 256) {
        int c = tid;
        float v0 = red[c * 4] + red[c * 4 + 1] + red[c * 4 + 2] + red[c * 4 + 3];
        int c2 = tid + 256;
        float v1 = red[c2 * 4] + red[c2 * 4 + 1] + red[c2 * 4 + 2] + red[c2 * 4 + 3];
        kws[(size_t)(b * 512 + c) * 64 + w] = v0;
        kws[(size_t)(b * 512 + c2) * 64 + w] = v1;
    }
}

// ---------- scores + top-8 per bh ------------------------------------------
__global__ void score_topk(const float* __restrict__ qp, const float* __restrict__ khs,
                           const float* __restrict__ kws, int* __restrict__ idx_h, int* __restrict__ idx_w)
{
    int bh = blockIdx.x;
    int lane = threadIdx.x;
    float sr = 0.f, sc = 0.f;
    for (int c = 0; c < 64; c++) {
        float q = qp[bh * 64 + c];
        sr = fmaf(q, khs[(size_t)(bh * 64 + c) * 64 + lane], sr);
        sc = fmaf(q, kws[(size_t)(bh * 64 + c) * 64 + lane], sc);
    }
    float v = sr;
    for (int it = 0; it < 8; it++) {
        float bv = v; int bi = lane;
        for (int off = 1; off < 64; off <<= 1) {
            float ov = __shfl_xor(bv, off, 64);
            int oi = __shfl_xor(bi, off, 64);
            if (ov > bv || (ov == bv && oi < bi)) { bv = ov; bi = oi; }
        }
        if (lane == 0) idx_h[bh * 8 + it] = bi;
        if (lane == bi) v = -INFINITY;
    }
    v = sc;
    for (int it = 0; it < 8; it++) {
        float bv = v; int bi = lane;
        for (int off = 1; off < 64; off <<= 1) {
            float ov = __shfl_xor(bv, off, 64);
            int oi = __shfl_xor(bi, off, 64);
            if (ov > bv || (ov == bv && oi < bi)) { bv = ov; bi = oi; }
        }
        if (lane == 0) idx_w[bh * 8 + it] = bi;
        if (lane == bi) v = -INFINITY;
    }
}

// ---------- gather k rows; compute v at selected pixels ---------------------
__global__ void gather_kv(const unsigned short* __restrict__ kbf, const unsigned short* __restrict__ ctx_t,
                          const float* __restrict__ wv_g, const float* __restrict__ Av, const float* __restrict__ Cv,
                          const float* __restrict__ ctx_m, const float* __restrict__ ctx_r,
                          const int* __restrict__ idx_h, const int* __restrict__ idx_w,
                          unsigned short* __restrict__ kg, unsigned short* __restrict__ vgt)
{
    int blk = blockIdx.x;    // bh*64 + key
    int bh = blk >> 6, j = blk & 63;
    int h = idx_h[bh * 8 + (j >> 3)];
    int w = idx_w[bh * 8 + (j & 7)];
    int p = h * 64 + w;
    int b = bh >> 3, head = bh & 7;
    int d = threadIdx.x;     // 64
    kg[(size_t)blk * 64 + d] = kbf[(size_t)(b * HW + p) * 512 + head * 64 + d];
    __shared__ float cx[DIM];
    const unsigned short* crow = ctx_t + (size_t)(b * HW + p) * 512;
    short8 cv = ((const short8*)crow)[d];
#pragma unroll
    for (int u = 0; u < 8; u++) cx[d * 8 + u] = bf2f((unsigned short)cv[u]);
    __syncthreads();
    int o = head * 64 + d;
    const float* wrow = wv_g + (size_t)o * DIM;
    float acc = 0.f;
    for (int i = 0; i < DIM; i++) acc = fmaf(wrow[i], cx[i], acc);
    int pix = b * HW + p;
    float v = ctx_r[pix] * (acc - ctx_m[pix] * Av[o]) + Cv[o];
    vgt[((size_t)bh * 64 + d) * 64 + j] = f2bf(v);
}

// ---------- MFMA attention: S^T = K·Q^T, softmax over m, O^T = Vt·P ---------
#define PROW 72  // padded per-query LDS row stride (bf16)
__global__ __launch_bounds__(256) void attn_mfma(
    const unsigned short* __restrict__ qbf, const unsigned short* __restrict__ kg,
    const unsigned short* __restrict__ vgt, unsigned short* __restrict__ abuf)
{
    int bh = blockIdx.y;
    int b = bh >> 3, head = bh & 7;
    int tid = threadIdx.x;
    int lane = tid & 63, wave = tid >> 6;
    int g = lane >> 4, l16 = lane & 15;
    int p0 = blockIdx.x * 256 + wave * 64;

    __shared__ unsigned short Plds[4][64 * PROW];
    unsigned short* P = Plds[wave];

    const unsigned short* kgb = kg + (size_t)bh * 4096;
    const unsigned short* vtb = vgt + (size_t)bh * 4096;
    const unsigned short* qb = qbf + (size_t)(b * HW) * 512 + head * 64;

    short8 Qf[4][2];
#pragma unroll
    for (int j = 0; j < 4; j++)
#pragma unroll
        for (int t = 0; t < 2; t++)
            Qf[j][t] = *(const short8*)(qb + (size_t)(p0 + j * 16 + l16) * 512 + t * 32 + g * 8);

    f32x4 S[4][4];
#pragma unroll
    for (int i = 0; i < 4; i++)
#pragma unroll
        for (int j = 0; j < 4; j++) S[i][j] = (f32x4){0.f, 0.f, 0.f, 0.f};
#pragma unroll
    for (int t = 0; t < 2; t++) {
        short8 Kf[4];
#pragma unroll
        for (int i = 0; i < 4; i++)
            Kf[i] = *(const short8*)(kgb + (i * 16 + l16) * 64 + t * 32 + g * 8);
#pragma unroll
        for (int i = 0; i < 4; i++)
#pragma unroll
            for (int j = 0; j < 4; j++)
                S[i][j] = __builtin_amdgcn_mfma_f32_16x16x32_bf16(Kf[i], Qf[j][t], S[i][j], 0, 0, 0);
    }

    float inv[4];
#pragma unroll
    for (int j = 0; j < 4; j++) {
        float e[4][4];
        float s = 0.f;
#pragma unroll
        for (int i = 0; i < 4; i++)
#pragma unroll
            for (int r = 0; r < 4; r++) { e[i][r] = __expf(S[i][j][r]); s += e[i][r]; }
        s += __shfl_xor(s, 16, 64);
        s += __shfl_xor(s, 32, 64);
        inv[j] = 1.0f / s;
        int row = j * 16 + l16;
#pragma unroll
        for (int i = 0; i < 4; i++) {
            uint2 pk;
            pk.x = pack2(e[i][0], e[i][1]);
            pk.y = pack2(e[i][2], e[i][3]);
            *(uint2*)(P + row * PROW + i * 16 + g * 4) = pk;
        }
    }

    f32x4 O[4][4];
#pragma unroll
    for (int i = 0; i < 4; i++)
#pragma unroll
        for (int j = 0; j < 4; j++) O[i][j] = (f32x4){0.f, 0.f, 0.f, 0.f};
#pragma unroll
    for (int t = 0; t < 2; t++) {
        short8 Vf[4], Pf[4];
#pragma unroll
        for (int i = 0; i < 4; i++)
            Vf[i] = *(const short8*)(vtb + (i * 16 + l16) * 64 + t * 32 + g * 8);
#pragma unroll
        for (int j = 0; j < 4; j++)
            Pf[j] = *(const short8*)(P + (j * 16 + l16) * PROW + t * 32 + g * 8);
#pragma unroll
        for (int i = 0; i < 4; i++)
#pragma unroll
            for (int j = 0; j < 4; j++)
                O[i][j] = __builtin_amdgcn_mfma_f32_16x16x32_bf16(Vf[i], Pf[j], O[i][j], 0, 0, 0);
    }

    unsigned short* ob = abuf + (size_t)(b * HW) * 512 + head * 64;
#pragma unroll
    for (int j = 0; j < 4; j++) {
        int p = p0 + j * 16 + l16;
#pragma unroll
        for (int i = 0; i < 4; i++) {
            uint2 pk;
            pk.x = pack2(O[i][j][0] * inv[j], O[i][j][1] * inv[j]);
            pk.y = pack2(O[i][j][2] * inv[j], O[i][j][3] * inv[j]);
            *(uint2*)(ob + (size_t)p * 512 + i * 16 + g * 4) = pk;
        }
    }
}

extern "C" void kernel_launch(void* const* d_in, const int* in_sizes, int n_in,
                              void* d_out, int out_size, void* d_ws, size_t ws_size,
                              hipStream_t stream)
{
    (void)in_sizes; (void)n_in; (void)out_size; (void)ws_size;
    const float* ctx   = (const float*)d_in[0];
    const float* qs    = (const float*)d_in[1];
    const float* ctx_g = (const float*)d_in[2];
    const float* ctx_b = (const float*)d_in[3];
    const float* qs_g  = (const float*)d_in[4];
    const float* qs_b  = (const float*)d_in[5];
    const float* w_q   = (const float*)d_in[6];
    const float* w_kv  = (const float*)d_in[7];
    const float* w_out = (const float*)d_in[8];
    const float* gamma = (const float*)d_in[9];
    float* out = (float*)d_out;

    char* base = (char*)d_ws;
    unsigned short* ctx_t = (unsigned short*)base;                 // 32 MB
    unsigned short* abuf  = ctx_t;                                 // alias after gather
    unsigned short* qs_t  = (unsigned short*)(base + ((size_t)32 << 20));
    unsigned short* kbf   = qs_t;                                  // alias after q-GEMM... (qs_t dead post k-GEMM staging read)
    unsigned short* qbf   = (unsigned short*)(base + ((size_t)64 << 20));
    char* tail = base + ((size_t)96 << 20);
    unsigned short* wq_b = (unsigned short*)tail;                  // 262144 elems
    unsigned short* wk_b = wq_b + 262144;
    unsigned short* wo_b = wk_b + 262144;
    float* wv_g  = (float*)(wo_b + 262144);                        // 262144 f
    float* Avec  = wv_g + 262144;                                  // 1536
    float* Cvec  = Avec + 1536;
    float* ctx_m = Cvec + 1536;                                    // 32768 each
    float* ctx_r = ctx_m + 32768;
    float* qs_m  = ctx_r + 32768;
    float* qs_r  = qs_m + 32768;
    float* qp    = qs_r + 32768;                                   // 4096
    float* khs   = qp + 4096;                                      // 262144
    float* kws   = khs + 262144;                                   // 262144
    int*   idxh  = (int*)(kws + 262144);                           // 512
    int*   idxw  = idxh + 512;
    unsigned short* kg  = (unsigned short*)(idxw + 512);           // 262144 bf16
    unsigned short* vgt = kg + 262144;                             // 262144 bf16

    hipMemsetAsync(qp, 0, 4096 * sizeof(float), stream);
    hipMemsetAsync(khs, 0, 262144 * sizeof(float), stream);

    prep_weights<<<2048, 256, 0, stream>>>(w_q, w_kv, w_out, ctx_g, ctx_b, qs_g, qs_b,
                                           wq_b, wk_b, wo_b, wv_g, Avec, Cvec);
    conv_stats<<<dim3(128, 8, 2), 256, 0, stream>>>(ctx, qs, ctx_t, qs_t,
                                                    ctx_m, ctx_r, qs_m, qs_r);
    gemm_mfma<0><<<dim3(32, 4, 8), 256, 0, stream>>>(wq_b, qs_t, nullptr, qbf, qs_m, qs_r,
                                                     Avec, Cvec, qp, nullptr, nullptr, nullptr, nullptr);
    gemm_mfma<1><<<dim3(32, 4, 8), 256, 0, stream>>>(wk_b, ctx_t, nullptr, kbf, ctx_m, ctx_r,
                                                     Avec + 512, Cvec + 512, khs, nullptr, nullptr, nullptr, nullptr);
    kws_kernel<<<512, 256, 0, stream>>>(kbf, kws);
    score_topk<<<64, 64, 0, stream>>>(qp, khs, kws, idxh, idxw);
    gather_kv<<<4096, 64, 0, stream>>>(kbf, ctx_t, wv_g, Avec + 1024, Cvec + 1024,
                                       ctx_m, ctx_r, idxh, idxw, kg, vgt);
    attn_mfma<<<dim3(16, 64), 256, 0, stream>>>(qbf, kg, vgt, abuf);
    gemm_mfma<2><<<dim3(32, 4, 8), 256, 0, stream>>>(wo_b, abuf, out, nullptr, qs_m, qs_r,
                                                     nullptr, nullptr, nullptr, qs, qs_g, qs_b, gamma);
}

// Round 6
// 449.491 us; speedup vs baseline: 1.0434x; 1.0434x over previous
//
#include <hip/hip_runtime.h>
#include <math.h>

#define HW 4096
#define DIM 512

typedef __attribute__((ext_vector_type(8))) short short8;
typedef __attribute__((ext_vector_type(4))) float f32x4;

__device__ inline unsigned short f2bf(float f) {
    unsigned int u = __float_as_uint(f);
    u += 0x7fff + ((u >> 16) & 1);   // round-to-nearest-even
    return (unsigned short)(u >> 16);
}
__device__ inline float bf2f(unsigned short h) {
    return __uint_as_float(((unsigned int)h) << 16);
}
__device__ inline unsigned pack2(float a, float b) {
    return (unsigned)f2bf(a) | ((unsigned)f2bf(b) << 16);
}

// async global->LDS, 16 B per lane. LDS dest = wave-uniform base + lane*16.
__device__ inline void gld16(const void* g, void* lds) {
    __builtin_amdgcn_global_load_lds(
        (const __attribute__((address_space(1))) unsigned int*)g,
        (__attribute__((address_space(3))) unsigned int*)lds, 16, 0, 0);
}

// ---------- prep weights: bf16 w*g for q/k, fp32 w*g for v, bf16 w_out ------
__global__ void prep_weights(const float* __restrict__ w_q, const float* __restrict__ w_kv,
                             const float* __restrict__ w_out,
                             const float* __restrict__ ctx_g, const float* __restrict__ ctx_b,
                             const float* __restrict__ qs_g, const float* __restrict__ qs_b,
                             unsigned short* __restrict__ wq_b, unsigned short* __restrict__ wk_b,
                             unsigned short* __restrict__ wo_b, float* __restrict__ wv_g,
                             float* __restrict__ Avec, float* __restrict__ Cvec)
{
    int blk = blockIdx.x;
    int widx = blk >> 9;
    int o = blk & 511;
    int tid = threadIdx.x;
    const float *src, *g = nullptr, *beta = nullptr;
    if (widx == 0)      { src = w_q  + (size_t)o * DIM; g = qs_g;  beta = qs_b; }
    else if (widx == 1) { src = w_kv + (size_t)o * DIM; g = ctx_g; beta = ctx_b; }
    else if (widx == 2) { src = w_kv + (size_t)(512 + o) * DIM; g = ctx_g; beta = ctx_b; }
    else                { src = w_out + (size_t)o * DIM; }
    float a = 0.f, c = 0.f;
    for (int i = tid; i < DIM; i += 256) {
        float w = src[i];
        if (widx == 3) { wo_b[(size_t)o * DIM + i] = f2bf(w); continue; }
        float wg = w * g[i];
        if (widx == 0)      wq_b[(size_t)o * DIM + i] = f2bf(wg);
        else if (widx == 1) wk_b[(size_t)o * DIM + i] = f2bf(wg);
        else                wv_g[(size_t)o * DIM + i] = wg;
        a += wg; c += w * beta[i];
    }
    if (widx == 3) return;  // uniform across block
    __shared__ float sa[256], sc[256];
    sa[tid] = a; sc[tid] = c;
    __syncthreads();
    for (int s = 128; s > 0; s >>= 1) {
        if (tid < s) { sa[tid] += sa[tid + s]; sc[tid] += sc[tid + s]; }
        __syncthreads();
    }
    if (tid == 0) { Avec[widx * 512 + o] = sa[0]; Cvec[widx * 512 + o] = sc[0]; }
}

// ---------- fused fp32->bf16 transpose + chan stats, register-only ----------
// (R2 version: best measured 66-67 us; latency-floored, leave alone.)
__global__ __launch_bounds__(256) void conv_stats(
    const float* __restrict__ ctx, const float* __restrict__ qs,
    unsigned short* __restrict__ ctx_t, unsigned short* __restrict__ qs_t,
    float* __restrict__ ctx_m, float* __restrict__ ctx_r,
    float* __restrict__ qs_m, float* __restrict__ qs_r)
{
    int which = blockIdx.z;
    int b = blockIdx.y;
    int p0 = blockIdx.x * 32;
    const float* X = (which ? qs : ctx) + (size_t)b * DIM * HW;
    unsigned short* Xt = (which ? qs_t : ctx_t) + (size_t)b * HW * DIM;
    int tid = threadIdx.x;
    int pg = tid & 7;          // pixel group: 4 consecutive pixels
    int cR = tid >> 3;         // 0..31: channel row (8 consecutive channels)

    const float* src0 = X + p0 + pg * 4;

    float4 s4 = {0.f, 0.f, 0.f, 0.f};
    float4 q4 = {0.f, 0.f, 0.f, 0.f};
    float4 buf[2][8];

#pragma unroll
    for (int it = 0; it < 2; it++)
#pragma unroll
        for (int j = 0; j < 8; j++)
            buf[it][j] = *(const float4*)(src0 + (size_t)(it * 256 + cR * 8 + j) * HW);

#pragma unroll
    for (int it = 0; it < 2; it++) {
        unsigned short* dst = Xt + (size_t)(p0 + pg * 4) * 512 + it * 256 + cR * 8;
        uint4 o;
        o.x = pack2(buf[it][0].x, buf[it][1].x);
        o.y = pack2(buf[it][2].x, buf[it][3].x);
        o.z = pack2(buf[it][4].x, buf[it][5].x);
        o.w = pack2(buf[it][6].x, buf[it][7].x);
        *(uint4*)(dst) = o;
        o.x = pack2(buf[it][0].y, buf[it][1].y);
        o.y = pack2(buf[it][2].y, buf[it][3].y);
        o.z = pack2(buf[it][4].y, buf[it][5].y);
        o.w = pack2(buf[it][6].y, buf[it][7].y);
        *(uint4*)(dst + 512) = o;
        o.x = pack2(buf[it][0].z, buf[it][1].z);
        o.y = pack2(buf[it][2].z, buf[it][3].z);
        o.z = pack2(buf[it][4].z, buf[it][5].z);
        o.w = pack2(buf[it][6].z, buf[it][7].z);
        *(uint4*)(dst + 1024) = o;
        o.x = pack2(buf[it][0].w, buf[it][1].w);
        o.y = pack2(buf[it][2].w, buf[it][3].w);
        o.z = pack2(buf[it][4].w, buf[it][5].w);
        o.w = pack2(buf[it][6].w, buf[it][7].w);
        *(uint4*)(dst + 1536) = o;
#pragma unroll
        for (int j = 0; j < 8; j++) {
            float4 v = buf[it][j];
            s4.x += v.x; s4.y += v.y; s4.z += v.z; s4.w += v.w;
            q4.x = fmaf(v.x, v.x, q4.x);
            q4.y = fmaf(v.y, v.y, q4.y);
            q4.z = fmaf(v.z, v.z, q4.z);
            q4.w = fmaf(v.w, v.w, q4.w);
        }
    }

#pragma unroll
    for (int off = 8; off <= 32; off <<= 1) {
        s4.x += __shfl_xor(s4.x, off, 64);
        s4.y += __shfl_xor(s4.y, off, 64);
        s4.z += __shfl_xor(s4.z, off, 64);
        s4.w += __shfl_xor(s4.w, off, 64);
        q4.x += __shfl_xor(q4.x, off, 64);
        q4.y += __shfl_xor(q4.y, off, 64);
        q4.z += __shfl_xor(q4.z, off, 64);
        q4.w += __shfl_xor(q4.w, off, 64);
    }

    __shared__ float sRed[4 * 32], qRed[4 * 32];
    int wave = tid >> 6, lane = tid & 63;
    if (lane < 8) {
        int base = wave * 32 + lane * 4;
        sRed[base + 0] = s4.x; sRed[base + 1] = s4.y;
        sRed[base + 2] = s4.z; sRed[base + 3] = s4.w;
        qRed[base + 0] = q4.x; qRed[base + 1] = q4.y;
        qRed[base + 2] = q4.z; qRed[base + 3] = q4.w;
    }
    __syncthreads();
    if (tid < 32) {
        float s = sRed[tid] + sRed[32 + tid] + sRed[64 + tid] + sRed[96 + tid];
        float q = qRed[tid] + qRed[32 + tid] + qRed[64 + tid] + qRed[96 + tid];
        float m = s * (1.0f / DIM);
        float var = q * (1.0f / DIM) - m * m;
        float r = 1.0f / sqrtf(var + 1e-5f);
        int pix = b * HW + p0 + tid;
        if (which == 0) { ctx_m[pix] = m; ctx_r[pix] = r; }
        else            { qs_m[pix]  = m; qs_r[pix]  = r; }
    }
}

// ---------- bf16 MFMA GEMM, 128x128 tile, BK=32 (R1 structure) --------------
// HEAD-MAJOR q/k/attn buffers: Ybf / abuf are [b*8+head][pixel][64] so that
// per-head consumers (attn, kws, gather) stream contiguously.
// MODE 0: q proj -> l2norm -> head-major bf16; |.| sums -> probe[b*512+m]
// MODE 1: k proj -> l2norm -> head-major bf16; khs -> probe[(b*512+m)*64+h]
// MODE 2: out GEMM (B = head-major abuf) -> fp32 [m][p], gamma*acc + LN(qsrc)
template<int MODE>
__global__ __launch_bounds__(256) void gemm_mfma(
    const unsigned short* __restrict__ Wb, const unsigned short* __restrict__ Xt,
    float* __restrict__ Y, unsigned short* __restrict__ Ybf,
    const float* __restrict__ mean, const float* __restrict__ rstd,
    const float* __restrict__ Arow, const float* __restrict__ Crow,
    float* __restrict__ probe,
    const float* __restrict__ qsrc, const float* __restrict__ g,
    const float* __restrict__ beta, const float* __restrict__ gammaPtr)
{
    int b = blockIdx.z;
    int n0 = blockIdx.x * 128;
    int m0 = blockIdx.y * 128;
    const unsigned short* Xb = Xt + (size_t)b * HW * DIM;   // MODE<2 only
    __shared__ uint4 AsBuf[512];   // 128 rows (m) x 32 k bf16
    __shared__ uint4 BsBuf[512];   // 128 rows (n) x 32 k bf16
    unsigned short* As = (unsigned short*)AsBuf;
    unsigned short* Bs = (unsigned short*)BsBuf;
    int tid = threadIdx.x;
    int lane = tid & 63;
    int wave = tid >> 6;
    int wbase = tid & 192;         // wave*64 (wave-uniform)
    int wm = (wave >> 1) * 64;
    int wn = (wave & 1) * 64;
    int quad = lane >> 4;
    int l16 = lane & 15;

    int r0 = tid >> 2, c0 = (tid & 3) * 8;
    const unsigned short* pA0 = Wb + (size_t)(m0 + r0) * DIM + c0;
    const unsigned short* pA1 = Wb + (size_t)(m0 + 64 + r0) * DIM + c0;
    const unsigned short* pB0 = Xb + (size_t)(n0 + r0) * DIM + c0;
    const unsigned short* pB1 = Xb + (size_t)(n0 + 64 + r0) * DIM + c0;

    f32x4 acc[4][4];
#pragma unroll
    for (int i = 0; i < 4; i++)
#pragma unroll
        for (int j = 0; j < 4; j++) acc[i][j] = (f32x4){0.f, 0.f, 0.f, 0.f};

    for (int kt = 0; kt < 16; kt++) {
        gld16(pA0, AsBuf + wbase);
        gld16(pA1, AsBuf + 256 + wbase);
        if (MODE == 2) {
            // B from head-major abuf: k-slice kt -> head kt>>1, half (kt&1)
            const unsigned short* pb = Xt +
                ((size_t)((b << 3) + (kt >> 1)) * HW + n0 + r0) * 64 + ((kt & 1) << 5) + c0;
            gld16(pb, BsBuf + wbase);
            gld16(pb + (size_t)64 * 64, BsBuf + 256 + wbase);
        } else {
            gld16(pB0, BsBuf + wbase);
            gld16(pB1, BsBuf + 256 + wbase);
            pB0 += 32; pB1 += 32;
        }
        pA0 += 32; pA1 += 32;
        __syncthreads();   // drains vmcnt -> staged data visible
        short8 af[4], bfr[4];
#pragma unroll
        for (int i = 0; i < 4; i++)
            af[i] = *(const short8*)(As + (wm + i * 16 + l16) * 32 + quad * 8);
#pragma unroll
        for (int j = 0; j < 4; j++)
            bfr[j] = *(const short8*)(Bs + (wn + j * 16 + l16) * 32 + quad * 8);
#pragma unroll
        for (int i = 0; i < 4; i++)
#pragma unroll
            for (int j = 0; j < 4; j++)
                acc[i][j] = __builtin_amdgcn_mfma_f32_16x16x32_bf16(af[i], bfr[j], acc[i][j], 0, 0, 0);
        __syncthreads();
    }

    if (MODE < 2) {
        int head = (m0 + wm) >> 6;   // wave's 64-ch m-block == one head
        float pa[4][4] = {};
#pragma unroll
        for (int j = 0; j < 4; j++) {
            int n = n0 + wn + j * 16 + l16;
            int pix = b * HW + n;
            float mn = mean[pix], rs = rstd[pix];
            float y[4][4];
            float s2 = 0.f;
#pragma unroll
            for (int i = 0; i < 4; i++) {
                int mb = m0 + wm + i * 16 + quad * 4;
#pragma unroll
                for (int r = 0; r < 4; r++) {
                    float v = rs * (acc[i][j][r] - mn * Arow[mb + r]) + Crow[mb + r];
                    y[i][r] = v;
                    s2 = fmaf(v, v, s2);
                }
            }
            // head l2-norm: wave spans exactly one 64-channel head in m
            s2 += __shfl_xor(s2, 16, 64);
            s2 += __shfl_xor(s2, 32, 64);
            float inv = 1.0f / fmaxf(sqrtf(s2), 1e-12f);
            // head-major write: [b*8+head][n][64]
            unsigned short* orow = Ybf + ((size_t)((b << 3) + head) * HW + n) * 64 + quad * 4;
#pragma unroll
            for (int i = 0; i < 4; i++) {
                float v0 = y[i][0] * inv, v1 = y[i][1] * inv;
                float v2 = y[i][2] * inv, v3 = y[i][3] * inv;
                uint2 pk; pk.x = pack2(v0, v1); pk.y = pack2(v2, v3);
                *(uint2*)(orow + i * 16) = pk;
                pa[i][0] += fabsf(v0); pa[i][1] += fabsf(v1);
                pa[i][2] += fabsf(v2); pa[i][3] += fabsf(v3);
            }
        }
#pragma unroll
        for (int i = 0; i < 4; i++)
#pragma unroll
            for (int r = 0; r < 4; r++) {
                float v = pa[i][r];
                v += __shfl_xor(v, 1, 64);
                v += __shfl_xor(v, 2, 64);
                v += __shfl_xor(v, 4, 64);
                v += __shfl_xor(v, 8, 64);
                pa[i][r] = v;
            }
        if (l16 == 0) {
#pragma unroll
            for (int i = 0; i < 4; i++)
#pragma unroll
                for (int r = 0; r < 4; r++) {
                    int m = m0 + wm + i * 16 + quad * 4 + r;
                    if (MODE == 0) atomicAdd(&probe[b * 512 + m], pa[i][r]);
                    else atomicAdd(&probe[(size_t)(b * 512 + m) * 64 + ((n0 + wn) >> 6)], pa[i][r]);
                }
        }
    } else {
        float* Yb = Y + (size_t)b * DIM * HW;
        float gamma = gammaPtr[0];
        const float* qb = qsrc + (size_t)b * DIM * HW;
#pragma unroll
        for (int j = 0; j < 4; j++) {
            int n = n0 + wn + j * 16 + l16;
            int pix = b * HW + n;
            float mn = mean[pix], rs = rstd[pix];
#pragma unroll
            for (int i = 0; i < 4; i++) {
                int mb = m0 + wm + i * 16 + quad * 4;
#pragma unroll
                for (int r = 0; r < 4; r++) {
                    int m = mb + r;
                    float qn = (qb[(size_t)m * HW + n] - mn) * rs * g[m] + beta[m];
                    Yb[(size_t)m * HW + n] = gamma * acc[i][j][r] + qn;
                }
            }
        }
    }
}

// ---------- kws[(b*512+c)][w] = sum_h |k[bh][h*64+w][c&63]|, head-major -----
__global__ __launch_bounds__(256) void kws_kernel(const unsigned short* __restrict__ kbf,
                                                  float* __restrict__ kws)
{
    int blk = blockIdx.x;     // b*64 + w
    int b = blk >> 6, w = blk & 63;
    int tid = threadIdx.x;
    int c8 = tid & 63;        // channel group of 8 (c = c8*8.. ; head = c8>>3)
    int hq = tid >> 6;        // 4 h-slices of 16
    const unsigned short* basep = kbf + ((size_t)((b << 3) + (c8 >> 3)) * HW) * 64 + (c8 & 7) * 8;
    float a[8] = {};
    for (int hh = 0; hh < 16; hh++) {
        int p = (hq * 16 + hh) * 64 + w;
        uint4 pk = *(const uint4*)(basep + (size_t)p * 64);
        const unsigned short* u = (const unsigned short*)&pk;
#pragma unroll
        for (int j = 0; j < 8; j++) a[j] += fabsf(bf2f(u[j]));
    }
    __shared__ float red[512 * 4];
#pragma unroll
    for (int j = 0; j < 8; j++) red[(c8 * 8 + j) * 4 + hq] = a[j];
    __syncthreads();
    if (tid < 256) {
        int c = tid;
        float v0 = red[c * 4] + red[c * 4 + 1] + red[c * 4 + 2] + red[c * 4 + 3];
        int c2 = tid + 256;
        float v1 = red[c2 * 4] + red[c2 * 4 + 1] + red[c2 * 4 + 2] + red[c2 * 4 + 3];
        kws[(size_t)(b * 512 + c) * 64 + w] = v0;
        kws[(size_t)(b * 512 + c2) * 64 + w] = v1;
    }
}

// ---------- scores + top-8 per bh ------------------------------------------
__global__ void score_topk(const float* __restrict__ qp, const float* __restrict__ khs,
                           const float* __restrict__ kws, int* __restrict__ idx_h, int* __restrict__ idx_w)
{
    int bh = blockIdx.x;
    int lane = threadIdx.x;
    float sr = 0.f, sc = 0.f;
    for (int c = 0; c < 64; c++) {
        float q = qp[bh * 64 + c];
        sr = fmaf(q, khs[(size_t)(bh * 64 + c) * 64 + lane], sr);
        sc = fmaf(q, kws[(size_t)(bh * 64 + c) * 64 + lane], sc);
    }
    float v = sr;
    for (int it = 0; it < 8; it++) {
        float bv = v; int bi = lane;
        for (int off = 1; off < 64; off <<= 1) {
            float ov = __shfl_xor(bv, off, 64);
            int oi = __shfl_xor(bi, off, 64);
            if (ov > bv || (ov == bv && oi < bi)) { bv = ov; bi = oi; }
        }
        if (lane == 0) idx_h[bh * 8 + it] = bi;
        if (lane == bi) v = -INFINITY;
    }
    v = sc;
    for (int it = 0; it < 8; it++) {
        float bv = v; int bi = lane;
        for (int off = 1; off < 64; off <<= 1) {
            float ov = __shfl_xor(bv, off, 64);
            int oi = __shfl_xor(bi, off, 64);
            if (ov > bv || (ov == bv && oi < bi)) { bv = ov; bi = oi; }
        }
        if (lane == 0) idx_w[bh * 8 + it] = bi;
        if (lane == bi) v = -INFINITY;
    }
}

// ---------- gather k rows (head-major); compute v at selected pixels --------
__global__ void gather_kv(const unsigned short* __restrict__ kbf, const unsigned short* __restrict__ ctx_t,
                          const float* __restrict__ wv_g, const float* __restrict__ Av, const float* __restrict__ Cv,
                          const float* __restrict__ ctx_m, const float* __restrict__ ctx_r,
                          const int* __restrict__ idx_h, const int* __restrict__ idx_w,
                          unsigned short* __restrict__ kg, unsigned short* __restrict__ vgt)
{
    int blk = blockIdx.x;    // bh*64 + key
    int bh = blk >> 6, j = blk & 63;
    int h = idx_h[bh * 8 + (j >> 3)];
    int w = idx_w[bh * 8 + (j & 7)];
    int p = h * 64 + w;
    int b = bh >> 3, head = bh & 7;
    int d = threadIdx.x;     // 64
    kg[(size_t)blk * 64 + d] = kbf[((size_t)bh * HW + p) * 64 + d];
    __shared__ float cx[DIM];
    const unsigned short* crow = ctx_t + (size_t)(b * HW + p) * 512;
    short8 cv = ((const short8*)crow)[d];
#pragma unroll
    for (int u = 0; u < 8; u++) cx[d * 8 + u] = bf2f((unsigned short)cv[u]);
    __syncthreads();
    int o = head * 64 + d;
    const float* wrow = wv_g + (size_t)o * DIM;
    float acc = 0.f;
    for (int i = 0; i < DIM; i++) acc = fmaf(wrow[i], cx[i], acc);
    int pix = b * HW + p;
    float v = ctx_r[pix] * (acc - ctx_m[pix] * Av[o]) + Cv[o];
    vgt[((size_t)bh * 64 + d) * 64 + j] = f2bf(v);
}

// ---------- MFMA attention (head-major q/O): S^T = K·Q^T, O^T = Vt·P --------
#define PROW 72  // padded per-query LDS row stride (bf16)
__global__ __launch_bounds__(256) void attn_mfma(
    const unsigned short* __restrict__ qbf, const unsigned short* __restrict__ kg,
    const unsigned short* __restrict__ vgt, unsigned short* __restrict__ abuf)
{
    int bh = blockIdx.y;
    int tid = threadIdx.x;
    int lane = tid & 63, wave = tid >> 6;
    int g = lane >> 4, l16 = lane & 15;
    int p0 = blockIdx.x * 256 + wave * 64;

    __shared__ unsigned short Plds[4][64 * PROW];
    unsigned short* P = Plds[wave];

    const unsigned short* kgb = kg + (size_t)bh * 4096;
    const unsigned short* vtb = vgt + (size_t)bh * 4096;
    const unsigned short* qb = qbf + (size_t)bh * HW * 64;   // head-major

    short8 Qf[4][2];
#pragma unroll
    for (int j = 0; j < 4; j++)
#pragma unroll
        for (int t = 0; t < 2; t++)
            Qf[j][t] = *(const short8*)(qb + (size_t)(p0 + j * 16 + l16) * 64 + t * 32 + g * 8);

    f32x4 S[4][4];
#pragma unroll
    for (int i = 0; i < 4; i++)
#pragma unroll
        for (int j = 0; j < 4; j++) S[i][j] = (f32x4){0.f, 0.f, 0.f, 0.f};
#pragma unroll
    for (int t = 0; t < 2; t++) {
        short8 Kf[4];
#pragma unroll
        for (int i = 0; i < 4; i++)
            Kf[i] = *(const short8*)(kgb + (i * 16 + l16) * 64 + t * 32 + g * 8);
#pragma unroll
        for (int i = 0; i < 4; i++)
#pragma unroll
            for (int j = 0; j < 4; j++)
                S[i][j] = __builtin_amdgcn_mfma_f32_16x16x32_bf16(Kf[i], Qf[j][t], S[i][j], 0, 0, 0);
    }

    float inv[4];
#pragma unroll
    for (int j = 0; j < 4; j++) {
        float e[4][4];
        float s = 0.f;
#pragma unroll
        for (int i = 0; i < 4; i++)
#pragma unroll
            for (int r = 0; r < 4; r++) { e[i][r] = __expf(S[i][j][r]); s += e[i][r]; }
        s += __shfl_xor(s, 16, 64);
        s += __shfl_xor(s, 32, 64);
        inv[j] = 1.0f / s;
        int row = j * 16 + l16;
#pragma unroll
        for (int i = 0; i < 4; i++) {
            uint2 pk;
            pk.x = pack2(e[i][0], e[i][1]);
            pk.y = pack2(e[i][2], e[i][3]);
            *(uint2*)(P + row * PROW + i * 16 + g * 4) = pk;
        }
    }

    f32x4 O[4][4];
#pragma unroll
    for (int i = 0; i < 4; i++)
#pragma unroll
        for (int j = 0; j < 4; j++) O[i][j] = (f32x4){0.f, 0.f, 0.f, 0.f};
#pragma unroll
    for (int t = 0; t < 2; t++) {
        short8 Vf[4], Pf[4];
#pragma unroll
        for (int i = 0; i < 4; i++)
            Vf[i] = *(const short8*)(vtb + (i * 16 + l16) * 64 + t * 32 + g * 8);
#pragma unroll
        for (int j = 0; j < 4; j++)
            Pf[j] = *(const short8*)(P + (j * 16 + l16) * PROW + t * 32 + g * 8);
#pragma unroll
        for (int i = 0; i < 4; i++)
#pragma unroll
            for (int j = 0; j < 4; j++)
                O[i][j] = __builtin_amdgcn_mfma_f32_16x16x32_bf16(Vf[i], Pf[j], O[i][j], 0, 0, 0);
    }

    unsigned short* ob = abuf + (size_t)bh * HW * 64;   // head-major
#pragma unroll
    for (int j = 0; j < 4; j++) {
        int p = p0 + j * 16 + l16;
#pragma unroll
        for (int i = 0; i < 4; i++) {
            uint2 pk;
            pk.x = pack2(O[i][j][0] * inv[j], O[i][j][1] * inv[j]);
            pk.y = pack2(O[i][j][2] * inv[j], O[i][j][3] * inv[j]);
            *(uint2*)(ob + (size_t)p * 64 + i * 16 + g * 4) = pk;
        }
    }
}

extern "C" void kernel_launch(void* const* d_in, const int* in_sizes, int n_in,
                              void* d_out, int out_size, void* d_ws, size_t ws_size,
                              hipStream_t stream)
{
    (void)in_sizes; (void)n_in; (void)out_size; (void)ws_size;
    const float* ctx   = (const float*)d_in[0];
    const float* qs    = (const float*)d_in[1];
    const float* ctx_g = (const float*)d_in[2];
    const float* ctx_b = (const float*)d_in[3];
    const float* qs_g  = (const float*)d_in[4];
    const float* qs_b  = (const float*)d_in[5];
    const float* w_q   = (const float*)d_in[6];
    const float* w_kv  = (const float*)d_in[7];
    const float* w_out = (const float*)d_in[8];
    const float* gamma = (const float*)d_in[9];
    float* out = (float*)d_out;

    char* base = (char*)d_ws;
    unsigned short* ctx_t = (unsigned short*)base;                 // 32 MB
    unsigned short* abuf  = ctx_t;                                 // alias after gather (head-major)
    unsigned short* qs_t  = (unsigned short*)(base + ((size_t)32 << 20));
    unsigned short* kbf   = qs_t;                                  // alias after q-GEMM (head-major k)
    unsigned short* qbf   = (unsigned short*)(base + ((size_t)64 << 20));  // head-major q
    char* tail = base + ((size_t)96 << 20);
    unsigned short* wq_b = (unsigned short*)tail;                  // 262144 elems
    unsigned short* wk_b = wq_b + 262144;
    unsigned short* wo_b = wk_b + 262144;
    float* wv_g  = (float*)(wo_b + 262144);                        // 262144 f
    float* Avec  = wv_g + 262144;                                  // 1536
    float* Cvec  = Avec + 1536;
    float* ctx_m = Cvec + 1536;                                    // 32768 each
    float* ctx_r = ctx_m + 32768;
    float* qs_m  = ctx_r + 32768;
    float* qs_r  = qs_m + 32768;
    float* qp    = qs_r + 32768;                                   // 4096
    float* khs   = qp + 4096;                                      // 262144
    float* kws   = khs + 262144;                                   // 262144
    int*   idxh  = (int*)(kws + 262144);                           // 512
    int*   idxw  = idxh + 512;
    unsigned short* kg  = (unsigned short*)(idxw + 512);           // 262144 bf16
    unsigned short* vgt = kg + 262144;                             // 262144 bf16

    hipMemsetAsync(qp, 0, 4096 * sizeof(float), stream);
    hipMemsetAsync(khs, 0, 262144 * sizeof(float), stream);

    prep_weights<<<2048, 256, 0, stream>>>(w_q, w_kv, w_out, ctx_g, ctx_b, qs_g, qs_b,
                                           wq_b, wk_b, wo_b, wv_g, Avec, Cvec);
    conv_stats<<<dim3(128, 8, 2), 256, 0, stream>>>(ctx, qs, ctx_t, qs_t,
                                                    ctx_m, ctx_r, qs_m, qs_r);
    gemm_mfma<0><<<dim3(32, 4, 8), 256, 0, stream>>>(wq_b, qs_t, nullptr, qbf, qs_m, qs_r,
                                                     Avec, Cvec, qp, nullptr, nullptr, nullptr, nullptr);
    gemm_mfma<1><<<dim3(32, 4, 8), 256, 0, stream>>>(wk_b, ctx_t, nullptr, kbf, ctx_m, ctx_r,
                                                     Avec + 512, Cvec + 512, khs, nullptr, nullptr, nullptr, nullptr);
    kws_kernel<<<512, 256, 0, stream>>>(kbf, kws);
    score_topk<<<64, 64, 0, stream>>>(qp, khs, kws, idxh, idxw);
    gather_kv<<<4096, 64, 0, stream>>>(kbf, ctx_t, wv_g, Avec + 1024, Cvec + 1024,
                                       ctx_m, ctx_r, idxh, idxw, kg, vgt);
    attn_mfma<<<dim3(16, 64), 256, 0, stream>>>(qbf, kg, vgt, abuf);
    gemm_mfma<2><<<dim3(32, 4, 8), 256, 0, stream>>>(wo_b, abuf, out, nullptr, qs_m, qs_r,
                                                     nullptr, nullptr, nullptr, qs, qs_g, qs_b, gamma);
}

// Round 7
// 438.054 us; speedup vs baseline: 1.0706x; 1.0261x over previous
//
#include <hip/hip_runtime.h>
#include <math.h>

#define HW 4096
#define DIM 512

typedef __attribute__((ext_vector_type(8))) short short8;
typedef __attribute__((ext_vector_type(4))) float f32x4;

__device__ inline unsigned short f2bf(float f) {
    unsigned int u = __float_as_uint(f);
    u += 0x7fff + ((u >> 16) & 1);   // round-to-nearest-even
    return (unsigned short)(u >> 16);
}
__device__ inline float bf2f(unsigned short h) {
    return __uint_as_float(((unsigned int)h) << 16);
}
__device__ inline unsigned pack2(float a, float b) {
    return (unsigned)f2bf(a) | ((unsigned)f2bf(b) << 16);
}

// async global->LDS, 16 B per lane. LDS dest = wave-uniform base + lane*16.
__device__ inline void gld16(const void* g, void* lds) {
    __builtin_amdgcn_global_load_lds(
        (const __attribute__((address_space(1))) unsigned int*)g,
        (__attribute__((address_space(3))) unsigned int*)lds, 16, 0, 0);
}

// ---------- fused: conv/transpose/stats (ids 0-2047) + weight prep (2048-
// 4095) + qp/khs zero-fill (4096-4160). Replaces 2 memsets + 2 kernels. ----
__global__ __launch_bounds__(256) void prep_conv(
    const float* __restrict__ ctx, const float* __restrict__ qs,
    unsigned short* __restrict__ ctx_t, unsigned short* __restrict__ qs_t,
    float* __restrict__ ctx_m, float* __restrict__ ctx_r,
    float* __restrict__ qs_m, float* __restrict__ qs_r,
    const float* __restrict__ w_q, const float* __restrict__ w_kv,
    const float* __restrict__ w_out,
    const float* __restrict__ ctx_g, const float* __restrict__ ctx_b,
    const float* __restrict__ qs_g, const float* __restrict__ qs_b,
    unsigned short* __restrict__ wq_b, unsigned short* __restrict__ wk_b,
    unsigned short* __restrict__ wo_b, float* __restrict__ wv_g,
    float* __restrict__ Avec, float* __restrict__ Cvec,
    float* __restrict__ zbase)
{
    int id = blockIdx.x;
    int tid = threadIdx.x;

    __shared__ float sa[256], sc[256];       // prep branch
    __shared__ float sRed[4 * 32], qRed[4 * 32];  // conv branch

    if (id >= 4096) {
        // zero qp (4096 f) + khs (262144 f): contiguous 266240 floats
        float4* p = (float4*)(zbase + (size_t)(id - 4096) * 4096 + tid * 16);
        float4 z = {0.f, 0.f, 0.f, 0.f};
        p[0] = z; p[1] = z; p[2] = z; p[3] = z;
        return;
    }

    if (id >= 2048) {
        // ---- prep_weights body (blk = id - 2048) ----
        int blk = id - 2048;
        int widx = blk >> 9;
        int o = blk & 511;
        const float *src, *g = nullptr, *beta = nullptr;
        if (widx == 0)      { src = w_q  + (size_t)o * DIM; g = qs_g;  beta = qs_b; }
        else if (widx == 1) { src = w_kv + (size_t)o * DIM; g = ctx_g; beta = ctx_b; }
        else if (widx == 2) { src = w_kv + (size_t)(512 + o) * DIM; g = ctx_g; beta = ctx_b; }
        else                { src = w_out + (size_t)o * DIM; }
        float a = 0.f, c = 0.f;
        for (int i = tid; i < DIM; i += 256) {
            float w = src[i];
            if (widx == 3) { wo_b[(size_t)o * DIM + i] = f2bf(w); continue; }
            float wg = w * g[i];
            if (widx == 0)      wq_b[(size_t)o * DIM + i] = f2bf(wg);
            else if (widx == 1) wk_b[(size_t)o * DIM + i] = f2bf(wg);
            else                wv_g[(size_t)o * DIM + i] = wg;
            a += wg; c += w * beta[i];
        }
        if (widx == 3) return;  // uniform across block
        sa[tid] = a; sc[tid] = c;
        __syncthreads();
        for (int s = 128; s > 0; s >>= 1) {
            if (tid < s) { sa[tid] += sa[tid + s]; sc[tid] += sc[tid + s]; }
            __syncthreads();
        }
        if (tid == 0) { Avec[widx * 512 + o] = sa[0]; Cvec[widx * 512 + o] = sc[0]; }
        return;
    }

    // ---- conv_stats body (R2/R1 register-only version, best measured) ----
    int xb = id & 127;
    int b = (id >> 7) & 7;
    int which = id >> 10;
    int p0 = xb * 32;
    const float* X = (which ? qs : ctx) + (size_t)b * DIM * HW;
    unsigned short* Xt = (which ? qs_t : ctx_t) + (size_t)b * HW * DIM;
    int pg = tid & 7;          // pixel group: 4 consecutive pixels
    int cR = tid >> 3;         // 0..31: channel row (8 consecutive channels)

    const float* src0 = X + p0 + pg * 4;

    float4 s4 = {0.f, 0.f, 0.f, 0.f};
    float4 q4 = {0.f, 0.f, 0.f, 0.f};
    float4 buf[2][8];

#pragma unroll
    for (int it = 0; it < 2; it++)
#pragma unroll
        for (int j = 0; j < 8; j++)
            buf[it][j] = *(const float4*)(src0 + (size_t)(it * 256 + cR * 8 + j) * HW);

#pragma unroll
    for (int it = 0; it < 2; it++) {
        unsigned short* dst = Xt + (size_t)(p0 + pg * 4) * 512 + it * 256 + cR * 8;
        uint4 o;
        o.x = pack2(buf[it][0].x, buf[it][1].x);
        o.y = pack2(buf[it][2].x, buf[it][3].x);
        o.z = pack2(buf[it][4].x, buf[it][5].x);
        o.w = pack2(buf[it][6].x, buf[it][7].x);
        *(uint4*)(dst) = o;
        o.x = pack2(buf[it][0].y, buf[it][1].y);
        o.y = pack2(buf[it][2].y, buf[it][3].y);
        o.z = pack2(buf[it][4].y, buf[it][5].y);
        o.w = pack2(buf[it][6].y, buf[it][7].y);
        *(uint4*)(dst + 512) = o;
        o.x = pack2(buf[it][0].z, buf[it][1].z);
        o.y = pack2(buf[it][2].z, buf[it][3].z);
        o.z = pack2(buf[it][4].z, buf[it][5].z);
        o.w = pack2(buf[it][6].z, buf[it][7].z);
        *(uint4*)(dst + 1024) = o;
        o.x = pack2(buf[it][0].w, buf[it][1].w);
        o.y = pack2(buf[it][2].w, buf[it][3].w);
        o.z = pack2(buf[it][4].w, buf[it][5].w);
        o.w = pack2(buf[it][6].w, buf[it][7].w);
        *(uint4*)(dst + 1536) = o;
#pragma unroll
        for (int j = 0; j < 8; j++) {
            float4 v = buf[it][j];
            s4.x += v.x; s4.y += v.y; s4.z += v.z; s4.w += v.w;
            q4.x = fmaf(v.x, v.x, q4.x);
            q4.y = fmaf(v.y, v.y, q4.y);
            q4.z = fmaf(v.z, v.z, q4.z);
            q4.w = fmaf(v.w, v.w, q4.w);
        }
    }

#pragma unroll
    for (int off = 8; off <= 32; off <<= 1) {
        s4.x += __shfl_xor(s4.x, off, 64);
        s4.y += __shfl_xor(s4.y, off, 64);
        s4.z += __shfl_xor(s4.z, off, 64);
        s4.w += __shfl_xor(s4.w, off, 64);
        q4.x += __shfl_xor(q4.x, off, 64);
        q4.y += __shfl_xor(q4.y, off, 64);
        q4.z += __shfl_xor(q4.z, off, 64);
        q4.w += __shfl_xor(q4.w, off, 64);
    }

    int wave = tid >> 6, lane = tid & 63;
    if (lane < 8) {
        int base = wave * 32 + lane * 4;
        sRed[base + 0] = s4.x; sRed[base + 1] = s4.y;
        sRed[base + 2] = s4.z; sRed[base + 3] = s4.w;
        qRed[base + 0] = q4.x; qRed[base + 1] = q4.y;
        qRed[base + 2] = q4.z; qRed[base + 3] = q4.w;
    }
    __syncthreads();
    if (tid < 32) {
        float s = sRed[tid] + sRed[32 + tid] + sRed[64 + tid] + sRed[96 + tid];
        float q = qRed[tid] + qRed[32 + tid] + qRed[64 + tid] + qRed[96 + tid];
        float m = s * (1.0f / DIM);
        float var = q * (1.0f / DIM) - m * m;
        float r = 1.0f / sqrtf(var + 1e-5f);
        int pix = b * HW + p0 + tid;
        if (which == 0) { ctx_m[pix] = m; ctx_r[pix] = r; }
        else            { qs_m[pix]  = m; qs_r[pix]  = r; }
    }
}

// ---------- merged projection GEMMs (q and k), R1 body, runtime `which` ----
// which = (z + zofs) >> 3: 0 = q-proj (qs_t -> qbf, probe qp),
//                          1 = k-proj (ctx_t -> kbf, probe khs).
// zofs allows a 2-launch fallback when kbf must alias qs_t (small ws).
__global__ __launch_bounds__(256) void gemm_proj(
    const unsigned short* __restrict__ wq_b, const unsigned short* __restrict__ wk_b,
    const unsigned short* __restrict__ qs_t, const unsigned short* __restrict__ ctx_t,
    unsigned short* __restrict__ qbf, unsigned short* __restrict__ kbf,
    const float* __restrict__ qs_m, const float* __restrict__ qs_r,
    const float* __restrict__ ctx_m, const float* __restrict__ ctx_r,
    const float* __restrict__ Avec, const float* __restrict__ Cvec,
    float* __restrict__ qp, float* __restrict__ khs, int zofs)
{
    int z = blockIdx.z + zofs;
    int which = z >> 3;
    int b = z & 7;
    const unsigned short* Wb = which ? wk_b : wq_b;
    const unsigned short* Xb = (which ? ctx_t : qs_t) + (size_t)b * HW * DIM;
    unsigned short* Ybf = which ? kbf : qbf;
    const float* mean = which ? ctx_m : qs_m;
    const float* rstd = which ? ctx_r : qs_r;
    const float* Arow = Avec + (which << 9);
    const float* Crow = Cvec + (which << 9);

    int n0 = blockIdx.x * 128;
    int m0 = blockIdx.y * 128;
    __shared__ uint4 AsBuf[512];   // 128 rows (m) x 32 k bf16
    __shared__ uint4 BsBuf[512];   // 128 rows (n) x 32 k bf16
    unsigned short* As = (unsigned short*)AsBuf;
    unsigned short* Bs = (unsigned short*)BsBuf;
    int tid = threadIdx.x;
    int lane = tid & 63;
    int wave = tid >> 6;
    int wbase = tid & 192;         // wave*64 (wave-uniform)
    int wm = (wave >> 1) * 64;
    int wn = (wave & 1) * 64;
    int quad = lane >> 4;
    int l16 = lane & 15;

    int r0 = tid >> 2, c0 = (tid & 3) * 8;
    const unsigned short* pA0 = Wb + (size_t)(m0 + r0) * DIM + c0;
    const unsigned short* pA1 = Wb + (size_t)(m0 + 64 + r0) * DIM + c0;
    const unsigned short* pB0 = Xb + (size_t)(n0 + r0) * DIM + c0;
    const unsigned short* pB1 = Xb + (size_t)(n0 + 64 + r0) * DIM + c0;

    f32x4 acc[4][4];
#pragma unroll
    for (int i = 0; i < 4; i++)
#pragma unroll
        for (int j = 0; j < 4; j++) acc[i][j] = (f32x4){0.f, 0.f, 0.f, 0.f};

    for (int kt = 0; kt < 16; kt++) {
        gld16(pA0, AsBuf + wbase);
        gld16(pA1, AsBuf + 256 + wbase);
        gld16(pB0, BsBuf + wbase);
        gld16(pB1, BsBuf + 256 + wbase);
        pA0 += 32; pA1 += 32; pB0 += 32; pB1 += 32;
        __syncthreads();   // drains vmcnt -> staged data visible
        short8 af[4], bfr[4];
#pragma unroll
        for (int i = 0; i < 4; i++)
            af[i] = *(const short8*)(As + (wm + i * 16 + l16) * 32 + quad * 8);
#pragma unroll
        for (int j = 0; j < 4; j++)
            bfr[j] = *(const short8*)(Bs + (wn + j * 16 + l16) * 32 + quad * 8);
#pragma unroll
        for (int i = 0; i < 4; i++)
#pragma unroll
            for (int j = 0; j < 4; j++)
                acc[i][j] = __builtin_amdgcn_mfma_f32_16x16x32_bf16(af[i], bfr[j], acc[i][j], 0, 0, 0);
        __syncthreads();
    }

    float pa[4][4] = {};
#pragma unroll
    for (int j = 0; j < 4; j++) {
        int n = n0 + wn + j * 16 + l16;
        int pix = b * HW + n;
        float mn = mean[pix], rs = rstd[pix];
        float y[4][4];
        float s2 = 0.f;
#pragma unroll
        for (int i = 0; i < 4; i++) {
            int mb = m0 + wm + i * 16 + quad * 4;
#pragma unroll
            for (int r = 0; r < 4; r++) {
                float v = rs * (acc[i][j][r] - mn * Arow[mb + r]) + Crow[mb + r];
                y[i][r] = v;
                s2 = fmaf(v, v, s2);
            }
        }
        // head l2-norm: wave spans exactly one 64-channel head in m
        s2 += __shfl_xor(s2, 16, 64);
        s2 += __shfl_xor(s2, 32, 64);
        float inv = 1.0f / fmaxf(sqrtf(s2), 1e-12f);
        unsigned short* orow = Ybf + (size_t)(b * HW + n) * 512 + m0 + wm + quad * 4;
#pragma unroll
        for (int i = 0; i < 4; i++) {
            float v0 = y[i][0] * inv, v1 = y[i][1] * inv;
            float v2 = y[i][2] * inv, v3 = y[i][3] * inv;
            uint2 pk; pk.x = pack2(v0, v1); pk.y = pack2(v2, v3);
            *(uint2*)(orow + i * 16) = pk;
            pa[i][0] += fabsf(v0); pa[i][1] += fabsf(v1);
            pa[i][2] += fabsf(v2); pa[i][3] += fabsf(v3);
        }
    }
#pragma unroll
    for (int i = 0; i < 4; i++)
#pragma unroll
        for (int r = 0; r < 4; r++) {
            float v = pa[i][r];
            v += __shfl_xor(v, 1, 64);
            v += __shfl_xor(v, 2, 64);
            v += __shfl_xor(v, 4, 64);
            v += __shfl_xor(v, 8, 64);
            pa[i][r] = v;
        }
    if (l16 == 0) {
#pragma unroll
        for (int i = 0; i < 4; i++)
#pragma unroll
            for (int r = 0; r < 4; r++) {
                int m = m0 + wm + i * 16 + quad * 4 + r;
                if (which == 0) atomicAdd(&qp[b * 512 + m], pa[i][r]);
                else atomicAdd(&khs[(size_t)(b * 512 + m) * 64 + ((n0 + wn) >> 6)], pa[i][r]);
            }
    }
}

// ---------- out GEMM (R1 MODE 2): fp32 [m][p], gamma*acc + LN(qsrc) --------
__global__ __launch_bounds__(256) void gemm_out(
    const unsigned short* __restrict__ Wb, const unsigned short* __restrict__ Xt,
    float* __restrict__ Y,
    const float* __restrict__ mean, const float* __restrict__ rstd,
    const float* __restrict__ qsrc, const float* __restrict__ g,
    const float* __restrict__ beta, const float* __restrict__ gammaPtr)
{
    int b = blockIdx.z;
    int n0 = blockIdx.x * 128;
    int m0 = blockIdx.y * 128;
    const unsigned short* Xb = Xt + (size_t)b * HW * DIM;
    __shared__ uint4 AsBuf[512];
    __shared__ uint4 BsBuf[512];
    unsigned short* As = (unsigned short*)AsBuf;
    unsigned short* Bs = (unsigned short*)BsBuf;
    int tid = threadIdx.x;
    int lane = tid & 63;
    int wave = tid >> 6;
    int wbase = tid & 192;
    int wm = (wave >> 1) * 64;
    int wn = (wave & 1) * 64;
    int quad = lane >> 4;
    int l16 = lane & 15;

    int r0 = tid >> 2, c0 = (tid & 3) * 8;
    const unsigned short* pA0 = Wb + (size_t)(m0 + r0) * DIM + c0;
    const unsigned short* pA1 = Wb + (size_t)(m0 + 64 + r0) * DIM + c0;
    const unsigned short* pB0 = Xb + (size_t)(n0 + r0) * DIM + c0;
    const unsigned short* pB1 = Xb + (size_t)(n0 + 64 + r0) * DIM + c0;

    f32x4 acc[4][4];
#pragma unroll
    for (int i = 0; i < 4; i++)
#pragma unroll
        for (int j = 0; j < 4; j++) acc[i][j] = (f32x4){0.f, 0.f, 0.f, 0.f};

    for (int kt = 0; kt < 16; kt++) {
        gld16(pA0, AsBuf + wbase);
        gld16(pA1, AsBuf + 256 + wbase);
        gld16(pB0, BsBuf + wbase);
        gld16(pB1, BsBuf + 256 + wbase);
        pA0 += 32; pA1 += 32; pB0 += 32; pB1 += 32;
        __syncthreads();
        short8 af[4], bfr[4];
#pragma unroll
        for (int i = 0; i < 4; i++)
            af[i] = *(const short8*)(As + (wm + i * 16 + l16) * 32 + quad * 8);
#pragma unroll
        for (int j = 0; j < 4; j++)
            bfr[j] = *(const short8*)(Bs + (wn + j * 16 + l16) * 32 + quad * 8);
#pragma unroll
        for (int i = 0; i < 4; i++)
#pragma unroll
            for (int j = 0; j < 4; j++)
                acc[i][j] = __builtin_amdgcn_mfma_f32_16x16x32_bf16(af[i], bfr[j], acc[i][j], 0, 0, 0);
        __syncthreads();
    }

    float* Yb = Y + (size_t)b * DIM * HW;
    float gamma = gammaPtr[0];
    const float* qb = qsrc + (size_t)b * DIM * HW;
#pragma unroll
    for (int j = 0; j < 4; j++) {
        int n = n0 + wn + j * 16 + l16;
        int pix = b * HW + n;
        float mn = mean[pix], rs = rstd[pix];
#pragma unroll
        for (int i = 0; i < 4; i++) {
            int mb = m0 + wm + i * 16 + quad * 4;
#pragma unroll
            for (int r = 0; r < 4; r++) {
                int m = mb + r;
                float qn = (qb[(size_t)m * HW + n] - mn) * rs * g[m] + beta[m];
                Yb[(size_t)m * HW + n] = gamma * acc[i][j][r] + qn;
            }
        }
    }
}

// ---------- kws[(b*512+c)][w] = sum_h |k[b][h*64+w][c]|, vectorized ---------
__global__ __launch_bounds__(256) void kws_kernel(const unsigned short* __restrict__ kbf,
                                                  float* __restrict__ kws)
{
    int blk = blockIdx.x;     // b*64 + w
    int b = blk >> 6, w = blk & 63;
    int tid = threadIdx.x;
    int c8 = tid & 63;        // channel group of 8
    int hq = tid >> 6;        // 4 h-slices of 16
    float a[8] = {};
    for (int hh = 0; hh < 16; hh++) {
        const unsigned short* row = kbf + ((size_t)(b * HW + (hq * 16 + hh) * 64 + w)) * 512 + c8 * 8;
        uint4 pk = *(const uint4*)row;
        const unsigned short* u = (const unsigned short*)&pk;
#pragma unroll
        for (int j = 0; j < 8; j++) a[j] += fabsf(bf2f(u[j]));
    }
    __shared__ float red[512 * 4];
#pragma unroll
    for (int j = 0; j < 8; j++) red[(c8 * 8 + j) * 4 + hq] = a[j];
    __syncthreads();
    if (tid < 256) {
        int c = tid;
        float v0 = red[c * 4] + red[c * 4 + 1] + red[c * 4 + 2] + red[c * 4 + 3];
        int c2 = tid + 256;
        float v1 = red[c2 * 4] + red[c2 * 4 + 1] + red[c2 * 4 + 2] + red[c2 * 4 + 3];
        kws[(size_t)(b * 512 + c) * 64 + w] = v0;
        kws[(size_t)(b * 512 + c2) * 64 + w] = v1;
    }
}

// ---------- scores + top-8 per bh ------------------------------------------
__global__ void score_topk(const float* __restrict__ qp, const float* __restrict__ khs,
                           const float* __restrict__ kws, int* __restrict__ idx_h, int* __restrict__ idx_w)
{
    int bh = blockIdx.x;
    int lane = threadIdx.x;
    float sr = 0.f, sc = 0.f;
    for (int c = 0; c < 64; c++) {
        float q = qp[bh * 64 + c];
        sr = fmaf(q, khs[(size_t)(bh * 64 + c) * 64 + lane], sr);
        sc = fmaf(q, kws[(size_t)(bh * 64 + c) * 64 + lane], sc);
    }
    float v = sr;
    for (int it = 0; it < 8; it++) {
        float bv = v; int bi = lane;
        for (int off = 1; off < 64; off <<= 1) {
            float ov = __shfl_xor(bv, off, 64);
            int oi = __shfl_xor(bi, off, 64);
            if (ov > bv || (ov == bv && oi < bi)) { bv = ov; bi = oi; }
        }
        if (lane == 0) idx_h[bh * 8 + it] = bi;
        if (lane == bi) v = -INFINITY;
    }
    v = sc;
    for (int it = 0; it < 8; it++) {
        float bv = v; int bi = lane;
        for (int off = 1; off < 64; off <<= 1) {
            float ov = __shfl_xor(bv, off, 64);
            int oi = __shfl_xor(bi, off, 64);
            if (ov > bv || (ov == bv && oi < bi)) { bv = ov; bi = oi; }
        }
        if (lane == 0) idx_w[bh * 8 + it] = bi;
        if (lane == bi) v = -INFINITY;
    }
}

// ---------- gather k rows; compute v at selected pixels ---------------------
__global__ void gather_kv(const unsigned short* __restrict__ kbf, const unsigned short* __restrict__ ctx_t,
                          const float* __restrict__ wv_g, const float* __restrict__ Av, const float* __restrict__ Cv,
                          const float* __restrict__ ctx_m, const float* __restrict__ ctx_r,
                          const int* __restrict__ idx_h, const int* __restrict__ idx_w,
                          unsigned short* __restrict__ kg, unsigned short* __restrict__ vgt)
{
    int blk = blockIdx.x;    // bh*64 + key
    int bh = blk >> 6, j = blk & 63;
    int h = idx_h[bh * 8 + (j >> 3)];
    int w = idx_w[bh * 8 + (j & 7)];
    int p = h * 64 + w;
    int b = bh >> 3, head = bh & 7;
    int d = threadIdx.x;     // 64
    kg[(size_t)blk * 64 + d] = kbf[(size_t)(b * HW + p) * 512 + head * 64 + d];
    __shared__ float cx[DIM];
    const unsigned short* crow = ctx_t + (size_t)(b * HW + p) * 512;
    short8 cv = ((const short8*)crow)[d];
#pragma unroll
    for (int u = 0; u < 8; u++) cx[d * 8 + u] = bf2f((unsigned short)cv[u]);
    __syncthreads();
    int o = head * 64 + d;
    const float* wrow = wv_g + (size_t)o * DIM;
    float acc = 0.f;
    for (int i = 0; i < DIM; i++) acc = fmaf(wrow[i], cx[i], acc);
    int pix = b * HW + p;
    float v = ctx_r[pix] * (acc - ctx_m[pix] * Av[o]) + Cv[o];
    vgt[((size_t)bh * 64 + d) * 64 + j] = f2bf(v);
}

// ---------- MFMA attention: S^T = K·Q^T, softmax over m, O^T = Vt·P ---------
#define PROW 72  // padded per-query LDS row stride (bf16)
__global__ __launch_bounds__(256) void attn_mfma(
    const unsigned short* __restrict__ qbf, const unsigned short* __restrict__ kg,
    const unsigned short* __restrict__ vgt, unsigned short* __restrict__ abuf)
{
    int bh = blockIdx.y;
    int b = bh >> 3, head = bh & 7;
    int tid = threadIdx.x;
    int lane = tid & 63, wave = tid >> 6;
    int g = lane >> 4, l16 = lane & 15;
    int p0 = blockIdx.x * 256 + wave * 64;

    __shared__ unsigned short Plds[4][64 * PROW];
    unsigned short* P = Plds[wave];

    const unsigned short* kgb = kg + (size_t)bh * 4096;
    const unsigned short* vtb = vgt + (size_t)bh * 4096;
    const unsigned short* qb = qbf + (size_t)(b * HW) * 512 + head * 64;

    short8 Qf[4][2];
#pragma unroll
    for (int j = 0; j < 4; j++)
#pragma unroll
        for (int t = 0; t < 2; t++)
            Qf[j][t] = *(const short8*)(qb + (size_t)(p0 + j * 16 + l16) * 512 + t * 32 + g * 8);

    f32x4 S[4][4];
#pragma unroll
    for (int i = 0; i < 4; i++)
#pragma unroll
        for (int j = 0; j < 4; j++) S[i][j] = (f32x4){0.f, 0.f, 0.f, 0.f};
#pragma unroll
    for (int t = 0; t < 2; t++) {
        short8 Kf[4];
#pragma unroll
        for (int i = 0; i < 4; i++)
            Kf[i] = *(const short8*)(kgb + (i * 16 + l16) * 64 + t * 32 + g * 8);
#pragma unroll
        for (int i = 0; i < 4; i++)
#pragma unroll
            for (int j = 0; j < 4; j++)
                S[i][j] = __builtin_amdgcn_mfma_f32_16x16x32_bf16(Kf[i], Qf[j][t], S[i][j], 0, 0, 0);
    }

    float inv[4];
#pragma unroll
    for (int j = 0; j < 4; j++) {
        float e[4][4];
        float s = 0.f;
#pragma unroll
        for (int i = 0; i < 4; i++)
#pragma unroll
            for (int r = 0; r < 4; r++) { e[i][r] = __expf(S[i][j][r]); s += e[i][r]; }
        s += __shfl_xor(s, 16, 64);
        s += __shfl_xor(s, 32, 64);
        inv[j] = 1.0f / s;
        int row = j * 16 + l16;
#pragma unroll
        for (int i = 0; i < 4; i++) {
            uint2 pk;
            pk.x = pack2(e[i][0], e[i][1]);
            pk.y = pack2(e[i][2], e[i][3]);
            *(uint2*)(P + row * PROW + i * 16 + g * 4) = pk;
        }
    }

    f32x4 O[4][4];
#pragma unroll
    for (int i = 0; i < 4; i++)
#pragma unroll
        for (int j = 0; j < 4; j++) O[i][j] = (f32x4){0.f, 0.f, 0.f, 0.f};
#pragma unroll
    for (int t = 0; t < 2; t++) {
        short8 Vf[4], Pf[4];
#pragma unroll
        for (int i = 0; i < 4; i++)
            Vf[i] = *(const short8*)(vtb + (i * 16 + l16) * 64 + t * 32 + g * 8);
#pragma unroll
        for (int j = 0; j < 4; j++)
            Pf[j] = *(const short8*)(P + (j * 16 + l16) * PROW + t * 32 + g * 8);
#pragma unroll
        for (int i = 0; i < 4; i++)
#pragma unroll
            for (int j = 0; j < 4; j++)
                O[i][j] = __builtin_amdgcn_mfma_f32_16x16x32_bf16(Vf[i], Pf[j], O[i][j], 0, 0, 0);
    }

    unsigned short* ob = abuf + (size_t)(b * HW) * 512 + head * 64;
#pragma unroll
    for (int j = 0; j < 4; j++) {
        int p = p0 + j * 16 + l16;
#pragma unroll
        for (int i = 0; i < 4; i++) {
            uint2 pk;
            pk.x = pack2(O[i][j][0] * inv[j], O[i][j][1] * inv[j]);
            pk.y = pack2(O[i][j][2] * inv[j], O[i][j][3] * inv[j]);
            *(uint2*)(ob + (size_t)p * 512 + i * 16 + g * 4) = pk;
        }
    }
}

extern "C" void kernel_launch(void* const* d_in, const int* in_sizes, int n_in,
                              void* d_out, int out_size, void* d_ws, size_t ws_size,
                              hipStream_t stream)
{
    (void)in_sizes; (void)n_in; (void)out_size;
    const float* ctx   = (const float*)d_in[0];
    const float* qs    = (const float*)d_in[1];
    const float* ctx_g = (const float*)d_in[2];
    const float* ctx_b = (const float*)d_in[3];
    const float* qs_g  = (const float*)d_in[4];
    const float* qs_b  = (const float*)d_in[5];
    const float* w_q   = (const float*)d_in[6];
    const float* w_kv  = (const float*)d_in[7];
    const float* w_out = (const float*)d_in[8];
    const float* gamma = (const float*)d_in[9];
    float* out = (float*)d_out;

    char* base = (char*)d_ws;
    // room for a dedicated kbf (needed to merge the two projection GEMMs)?
    bool sep = ws_size >= ((size_t)136 << 20);

    unsigned short* ctx_t = (unsigned short*)base;                 // 32 MB
    unsigned short* abuf  = ctx_t;                                 // alias after gather
    unsigned short* qs_t  = (unsigned short*)(base + ((size_t)32 << 20));
    unsigned short* qbf   = (unsigned short*)(base + ((size_t)64 << 20));
    unsigned short* kbf   = sep ? (unsigned short*)(base + ((size_t)96 << 20))
                                : qs_t;                            // fallback alias
    char* tail = base + (sep ? ((size_t)128 << 20) : ((size_t)96 << 20));
    unsigned short* wq_b = (unsigned short*)tail;                  // 262144 elems
    unsigned short* wk_b = wq_b + 262144;
    unsigned short* wo_b = wk_b + 262144;
    float* wv_g  = (float*)(wo_b + 262144);                        // 262144 f
    float* Avec  = wv_g + 262144;                                  // 1536
    float* Cvec  = Avec + 1536;
    float* ctx_m = Cvec + 1536;                                    // 32768 each
    float* ctx_r = ctx_m + 32768;
    float* qs_m  = ctx_r + 32768;
    float* qs_r  = qs_m + 32768;
    float* qp    = qs_r + 32768;                                   // 4096
    float* khs   = qp + 4096;                                      // 262144 (contiguous after qp)
    float* kws   = khs + 262144;                                   // 262144
    int*   idxh  = (int*)(kws + 262144);                           // 512
    int*   idxw  = idxh + 512;
    unsigned short* kg  = (unsigned short*)(idxw + 512);           // 262144 bf16
    unsigned short* vgt = kg + 262144;                             // 262144 bf16

    // fused: conv/transpose/stats + weight prep + qp/khs zeroing
    prep_conv<<<4161, 256, 0, stream>>>(ctx, qs, ctx_t, qs_t,
                                        ctx_m, ctx_r, qs_m, qs_r,
                                        w_q, w_kv, w_out, ctx_g, ctx_b, qs_g, qs_b,
                                        wq_b, wk_b, wo_b, wv_g, Avec, Cvec, qp);

    if (sep) {
        // both projection GEMMs in one dispatch (tails overlap)
        gemm_proj<<<dim3(32, 4, 16), 256, 0, stream>>>(
            wq_b, wk_b, qs_t, ctx_t, qbf, kbf,
            qs_m, qs_r, ctx_m, ctx_r, Avec, Cvec, qp, khs, 0);
    } else {
        // kbf aliases qs_t: q-proj (reads qs_t) must complete before k-proj
        gemm_proj<<<dim3(32, 4, 8), 256, 0, stream>>>(
            wq_b, wk_b, qs_t, ctx_t, qbf, kbf,
            qs_m, qs_r, ctx_m, ctx_r, Avec, Cvec, qp, khs, 0);
        gemm_proj<<<dim3(32, 4, 8), 256, 0, stream>>>(
            wq_b, wk_b, qs_t, ctx_t, qbf, kbf,
            qs_m, qs_r, ctx_m, ctx_r, Avec, Cvec, qp, khs, 8);
    }

    kws_kernel<<<512, 256, 0, stream>>>(kbf, kws);
    score_topk<<<64, 64, 0, stream>>>(qp, khs, kws, idxh, idxw);
    gather_kv<<<4096, 64, 0, stream>>>(kbf, ctx_t, wv_g, Avec + 1024, Cvec + 1024,
                                       ctx_m, ctx_r, idxh, idxw, kg, vgt);
    attn_mfma<<<dim3(16, 64), 256, 0, stream>>>(qbf, kg, vgt, abuf);
    gemm_out<<<dim3(32, 4, 8), 256, 0, stream>>>(wo_b, abuf, out, qs_m, qs_r,
                                                 qs, qs_g, qs_b, gamma);
}

// Round 9
// 434.865 us; speedup vs baseline: 1.0785x; 1.0073x over previous
//
#include <hip/hip_runtime.h>
#include <math.h>

#define HW 4096
#define DIM 512

typedef __attribute__((ext_vector_type(8))) short short8;
typedef __attribute__((ext_vector_type(4))) float f32x4;

__device__ inline unsigned short f2bf(float f) {
    unsigned int u = __float_as_uint(f);
    u += 0x7fff + ((u >> 16) & 1);   // round-to-nearest-even
    return (unsigned short)(u >> 16);
}
__device__ inline float bf2f(unsigned short h) {
    return __uint_as_float(((unsigned int)h) << 16);
}
__device__ inline unsigned pack2(float a, float b) {
    return (unsigned)f2bf(a) | ((unsigned)f2bf(b) << 16);
}

// async global->LDS, 16 B per lane. LDS dest = wave-uniform base + lane*16.
__device__ inline void gld16(const void* g, void* lds) {
    __builtin_amdgcn_global_load_lds(
        (const __attribute__((address_space(1))) unsigned int*)g,
        (__attribute__((address_space(3))) unsigned int*)lds, 16, 0, 0);
}

// ---------- fused: conv/transpose/stats (ids 0-2047) + weight prep (2048-
// 4095) + qp/khs zero-fill (4096-4160). Replaces 2 memsets + 2 kernels. ----
__global__ __launch_bounds__(256) void prep_conv(
    const float* __restrict__ ctx, const float* __restrict__ qs,
    unsigned short* __restrict__ ctx_t, unsigned short* __restrict__ qs_t,
    float* __restrict__ ctx_m, float* __restrict__ ctx_r,
    float* __restrict__ qs_m, float* __restrict__ qs_r,
    const float* __restrict__ w_q, const float* __restrict__ w_kv,
    const float* __restrict__ w_out,
    const float* __restrict__ ctx_g, const float* __restrict__ ctx_b,
    const float* __restrict__ qs_g, const float* __restrict__ qs_b,
    unsigned short* __restrict__ wq_b, unsigned short* __restrict__ wk_b,
    unsigned short* __restrict__ wo_b, float* __restrict__ wv_g,
    float* __restrict__ Avec, float* __restrict__ Cvec,
    float* __restrict__ zbase)
{
    int id = blockIdx.x;
    int tid = threadIdx.x;

    __shared__ float sa[256], sc[256];       // prep branch
    __shared__ float sRed[4 * 32], qRed[4 * 32];  // conv branch

    if (id >= 4096) {
        // zero qp (4096 f) + khs (262144 f): contiguous 266240 floats
        float4* p = (float4*)(zbase + (size_t)(id - 4096) * 4096 + tid * 16);
        float4 z = {0.f, 0.f, 0.f, 0.f};
        p[0] = z; p[1] = z; p[2] = z; p[3] = z;
        return;
    }

    if (id >= 2048) {
        // ---- prep_weights body (blk = id - 2048) ----
        int blk = id - 2048;
        int widx = blk >> 9;
        int o = blk & 511;
        const float *src, *g = nullptr, *beta = nullptr;
        if (widx == 0)      { src = w_q  + (size_t)o * DIM; g = qs_g;  beta = qs_b; }
        else if (widx == 1) { src = w_kv + (size_t)o * DIM; g = ctx_g; beta = ctx_b; }
        else if (widx == 2) { src = w_kv + (size_t)(512 + o) * DIM; g = ctx_g; beta = ctx_b; }
        else                { src = w_out + (size_t)o * DIM; }
        float a = 0.f, c = 0.f;
        for (int i = tid; i < DIM; i += 256) {
            float w = src[i];
            if (widx == 3) { wo_b[(size_t)o * DIM + i] = f2bf(w); continue; }
            float wg = w * g[i];
            if (widx == 0)      wq_b[(size_t)o * DIM + i] = f2bf(wg);
            else if (widx == 1) wk_b[(size_t)o * DIM + i] = f2bf(wg);
            else                wv_g[(size_t)o * DIM + i] = wg;
            a += wg; c += w * beta[i];
        }
        if (widx == 3) return;  // uniform across block
        sa[tid] = a; sc[tid] = c;
        __syncthreads();
        for (int s = 128; s > 0; s >>= 1) {
            if (tid < s) { sa[tid] += sa[tid + s]; sc[tid] += sc[tid + s]; }
            __syncthreads();
        }
        if (tid == 0) { Avec[widx * 512 + o] = sa[0]; Cvec[widx * 512 + o] = sc[0]; }
        return;
    }

    // ---- conv_stats body (R2/R1 register-only version, best measured) ----
    int xb = id & 127;
    int b = (id >> 7) & 7;
    int which = id >> 10;
    int p0 = xb * 32;
    const float* X = (which ? qs : ctx) + (size_t)b * DIM * HW;
    unsigned short* Xt = (which ? qs_t : ctx_t) + (size_t)b * HW * DIM;
    int pg = tid & 7;          // pixel group: 4 consecutive pixels
    int cR = tid >> 3;         // 0..31: channel row (8 consecutive channels)

    const float* src0 = X + p0 + pg * 4;

    float4 s4 = {0.f, 0.f, 0.f, 0.f};
    float4 q4 = {0.f, 0.f, 0.f, 0.f};
    float4 buf[2][8];

#pragma unroll
    for (int it = 0; it < 2; it++)
#pragma unroll
        for (int j = 0; j < 8; j++)
            buf[it][j] = *(const float4*)(src0 + (size_t)(it * 256 + cR * 8 + j) * HW);

#pragma unroll
    for (int it = 0; it < 2; it++) {
        unsigned short* dst = Xt + (size_t)(p0 + pg * 4) * 512 + it * 256 + cR * 8;
        uint4 o;
        o.x = pack2(buf[it][0].x, buf[it][1].x);
        o.y = pack2(buf[it][2].x, buf[it][3].x);
        o.z = pack2(buf[it][4].x, buf[it][5].x);
        o.w = pack2(buf[it][6].x, buf[it][7].x);
        *(uint4*)(dst) = o;
        o.x = pack2(buf[it][0].y, buf[it][1].y);
        o.y = pack2(buf[it][2].y, buf[it][3].y);
        o.z = pack2(buf[it][4].y, buf[it][5].y);
        o.w = pack2(buf[it][6].y, buf[it][7].y);
        *(uint4*)(dst + 512) = o;
        o.x = pack2(buf[it][0].z, buf[it][1].z);
        o.y = pack2(buf[it][2].z, buf[it][3].z);
        o.z = pack2(buf[it][4].z, buf[it][5].z);
        o.w = pack2(buf[it][6].z, buf[it][7].z);
        *(uint4*)(dst + 1024) = o;
        o.x = pack2(buf[it][0].w, buf[it][1].w);
        o.y = pack2(buf[it][2].w, buf[it][3].w);
        o.z = pack2(buf[it][4].w, buf[it][5].w);
        o.w = pack2(buf[it][6].w, buf[it][7].w);
        *(uint4*)(dst + 1536) = o;
#pragma unroll
        for (int j = 0; j < 8; j++) {
            float4 v = buf[it][j];
            s4.x += v.x; s4.y += v.y; s4.z += v.z; s4.w += v.w;
            q4.x = fmaf(v.x, v.x, q4.x);
            q4.y = fmaf(v.y, v.y, q4.y);
            q4.z = fmaf(v.z, v.z, q4.z);
            q4.w = fmaf(v.w, v.w, q4.w);
        }
    }

#pragma unroll
    for (int off = 8; off <= 32; off <<= 1) {
        s4.x += __shfl_xor(s4.x, off, 64);
        s4.y += __shfl_xor(s4.y, off, 64);
        s4.z += __shfl_xor(s4.z, off, 64);
        s4.w += __shfl_xor(s4.w, off, 64);
        q4.x += __shfl_xor(q4.x, off, 64);
        q4.y += __shfl_xor(q4.y, off, 64);
        q4.z += __shfl_xor(q4.z, off, 64);
        q4.w += __shfl_xor(q4.w, off, 64);
    }

    int wave = tid >> 6, lane = tid & 63;
    if (lane < 8) {
        int base = wave * 32 + lane * 4;
        sRed[base + 0] = s4.x; sRed[base + 1] = s4.y;
        sRed[base + 2] = s4.z; sRed[base + 3] = s4.w;
        qRed[base + 0] = q4.x; qRed[base + 1] = q4.y;
        qRed[base + 2] = q4.z; qRed[base + 3] = q4.w;
    }
    __syncthreads();
    if (tid < 32) {
        float s = sRed[tid] + sRed[32 + tid] + sRed[64 + tid] + sRed[96 + tid];
        float q = qRed[tid] + qRed[32 + tid] + qRed[64 + tid] + qRed[96 + tid];
        float m = s * (1.0f / DIM);
        float var = q * (1.0f / DIM) - m * m;
        float r = 1.0f / sqrtf(var + 1e-5f);
        int pix = b * HW + p0 + tid;
        if (which == 0) { ctx_m[pix] = m; ctx_r[pix] = r; }
        else            { qs_m[pix]  = m; qs_r[pix]  = r; }
    }
}

// ---------- merged projection GEMMs (q and k), swizzled LDS ----------------
// LDS 16-B-slot XOR swizzle (slot ^= (row>>1)&3) kills the 8-way bank
// conflict on ds_read_b128 (R7 PMC: 4.19M conflicts/dispatch). LDS dest of
// global_load_lds stays linear; the GLOBAL source column is pre-swizzled,
// and fragment reads apply the matching XOR ((row>>1)&3 == (l16>>1)&3).
__global__ __launch_bounds__(256) void gemm_proj(
    const unsigned short* __restrict__ wq_b, const unsigned short* __restrict__ wk_b,
    const unsigned short* __restrict__ qs_t, const unsigned short* __restrict__ ctx_t,
    unsigned short* __restrict__ qbf, unsigned short* __restrict__ kbf,
    const float* __restrict__ qs_m, const float* __restrict__ qs_r,
    const float* __restrict__ ctx_m, const float* __restrict__ ctx_r,
    const float* __restrict__ Avec, const float* __restrict__ Cvec,
    float* __restrict__ qp, float* __restrict__ khs, int zofs)
{
    int z = blockIdx.z + zofs;
    int which = z >> 3;
    int b = z & 7;
    const unsigned short* Wb = which ? wk_b : wq_b;
    const unsigned short* Xb = (which ? ctx_t : qs_t) + (size_t)b * HW * DIM;
    unsigned short* Ybf = which ? kbf : qbf;
    const float* mean = which ? ctx_m : qs_m;
    const float* rstd = which ? ctx_r : qs_r;
    const float* Arow = Avec + (which << 9);
    const float* Crow = Cvec + (which << 9);

    int n0 = blockIdx.x * 128;
    int m0 = blockIdx.y * 128;
    __shared__ uint4 AsBuf[512];   // 128 rows (m) x 32 k bf16
    __shared__ uint4 BsBuf[512];   // 128 rows (n) x 32 k bf16
    unsigned short* As = (unsigned short*)AsBuf;
    unsigned short* Bs = (unsigned short*)BsBuf;
    int tid = threadIdx.x;
    int lane = tid & 63;
    int wave = tid >> 6;
    int wbase = tid & 192;         // wave*64 (wave-uniform)
    int wm = (wave >> 1) * 64;
    int wn = (wave & 1) * 64;
    int quad = lane >> 4;
    int l16 = lane & 15;

    int r0 = tid >> 2;
    int c0 = (((tid & 3) ^ ((r0 >> 1) & 3)) * 8);   // pre-swizzled global col
    const unsigned short* pA0 = Wb + (size_t)(m0 + r0) * DIM + c0;
    const unsigned short* pA1 = Wb + (size_t)(m0 + 64 + r0) * DIM + c0;
    const unsigned short* pB0 = Xb + (size_t)(n0 + r0) * DIM + c0;
    const unsigned short* pB1 = Xb + (size_t)(n0 + 64 + r0) * DIM + c0;

    int fx = (l16 >> 1) & 3;       // fragment-read XOR

    f32x4 acc[4][4];
#pragma unroll
    for (int i = 0; i < 4; i++)
#pragma unroll
        for (int j = 0; j < 4; j++) acc[i][j] = (f32x4){0.f, 0.f, 0.f, 0.f};

    for (int kt = 0; kt < 16; kt++) {
        gld16(pA0, AsBuf + wbase);
        gld16(pA1, AsBuf + 256 + wbase);
        gld16(pB0, BsBuf + wbase);
        gld16(pB1, BsBuf + 256 + wbase);
        pA0 += 32; pA1 += 32; pB0 += 32; pB1 += 32;
        __syncthreads();   // drains vmcnt -> staged data visible
        short8 af[4], bfr[4];
#pragma unroll
        for (int i = 0; i < 4; i++)
            af[i] = *(const short8*)(As + (wm + i * 16 + l16) * 32 + ((quad ^ fx) * 8));
#pragma unroll
        for (int j = 0; j < 4; j++)
            bfr[j] = *(const short8*)(Bs + (wn + j * 16 + l16) * 32 + ((quad ^ fx) * 8));
#pragma unroll
        for (int i = 0; i < 4; i++)
#pragma unroll
            for (int j = 0; j < 4; j++)
                acc[i][j] = __builtin_amdgcn_mfma_f32_16x16x32_bf16(af[i], bfr[j], acc[i][j], 0, 0, 0);
        __syncthreads();
    }

    float pa[4][4] = {};
#pragma unroll
    for (int j = 0; j < 4; j++) {
        int n = n0 + wn + j * 16 + l16;
        int pix = b * HW + n;
        float mn = mean[pix], rs = rstd[pix];
        float y[4][4];
        float s2 = 0.f;
#pragma unroll
        for (int i = 0; i < 4; i++) {
            int mb = m0 + wm + i * 16 + quad * 4;
#pragma unroll
            for (int r = 0; r < 4; r++) {
                float v = rs * (acc[i][j][r] - mn * Arow[mb + r]) + Crow[mb + r];
                y[i][r] = v;
                s2 = fmaf(v, v, s2);
            }
        }
        // head l2-norm: wave spans exactly one 64-channel head in m
        s2 += __shfl_xor(s2, 16, 64);
        s2 += __shfl_xor(s2, 32, 64);
        float inv = 1.0f / fmaxf(sqrtf(s2), 1e-12f);
        unsigned short* orow = Ybf + (size_t)(b * HW + n) * 512 + m0 + wm + quad * 4;
#pragma unroll
        for (int i = 0; i < 4; i++) {
            float v0 = y[i][0] * inv, v1 = y[i][1] * inv;
            float v2 = y[i][2] * inv, v3 = y[i][3] * inv;
            uint2 pk; pk.x = pack2(v0, v1); pk.y = pack2(v2, v3);
            *(uint2*)(orow + i * 16) = pk;
            pa[i][0] += fabsf(v0); pa[i][1] += fabsf(v1);
            pa[i][2] += fabsf(v2); pa[i][3] += fabsf(v3);
        }
    }
#pragma unroll
    for (int i = 0; i < 4; i++)
#pragma unroll
        for (int r = 0; r < 4; r++) {
            float v = pa[i][r];
            v += __shfl_xor(v, 1, 64);
            v += __shfl_xor(v, 2, 64);
            v += __shfl_xor(v, 4, 64);
            v += __shfl_xor(v, 8, 64);
            pa[i][r] = v;
        }
    if (l16 == 0) {
#pragma unroll
        for (int i = 0; i < 4; i++)
#pragma unroll
            for (int r = 0; r < 4; r++) {
                int m = m0 + wm + i * 16 + quad * 4 + r;
                if (which == 0) atomicAdd(&qp[b * 512 + m], pa[i][r]);
                else atomicAdd(&khs[(size_t)(b * 512 + m) * 64 + ((n0 + wn) >> 6)], pa[i][r]);
            }
    }
}

// ---------- out GEMM: fp32 [m][p], gamma*acc + LN(qsrc), swizzled LDS ------
__global__ __launch_bounds__(256) void gemm_out(
    const unsigned short* __restrict__ Wb, const unsigned short* __restrict__ Xt,
    float* __restrict__ Y,
    const float* __restrict__ mean, const float* __restrict__ rstd,
    const float* __restrict__ qsrc, const float* __restrict__ g,
    const float* __restrict__ beta, const float* __restrict__ gammaPtr)
{
    int b = blockIdx.z;
    int n0 = blockIdx.x * 128;
    int m0 = blockIdx.y * 128;
    const unsigned short* Xb = Xt + (size_t)b * HW * DIM;
    __shared__ uint4 AsBuf[512];
    __shared__ uint4 BsBuf[512];
    unsigned short* As = (unsigned short*)AsBuf;
    unsigned short* Bs = (unsigned short*)BsBuf;
    int tid = threadIdx.x;
    int lane = tid & 63;
    int wave = tid >> 6;
    int wbase = tid & 192;
    int wm = (wave >> 1) * 64;
    int wn = (wave & 1) * 64;
    int quad = lane >> 4;
    int l16 = lane & 15;

    int r0 = tid >> 2;
    int c0 = (((tid & 3) ^ ((r0 >> 1) & 3)) * 8);   // pre-swizzled global col
    const unsigned short* pA0 = Wb + (size_t)(m0 + r0) * DIM + c0;
    const unsigned short* pA1 = Wb + (size_t)(m0 + 64 + r0) * DIM + c0;
    const unsigned short* pB0 = Xb + (size_t)(n0 + r0) * DIM + c0;
    const unsigned short* pB1 = Xb + (size_t)(n0 + 64 + r0) * DIM + c0;

    int fx = (l16 >> 1) & 3;

    f32x4 acc[4][4];
#pragma unroll
    for (int i = 0; i < 4; i++)
#pragma unroll
        for (int j = 0; j < 4; j++) acc[i][j] = (f32x4){0.f, 0.f, 0.f, 0.f};

    for (int kt = 0; kt < 16; kt++) {
        gld16(pA0, AsBuf + wbase);
        gld16(pA1, AsBuf + 256 + wbase);
        gld16(pB0, BsBuf + wbase);
        gld16(pB1, BsBuf + 256 + wbase);
        pA0 += 32; pA1 += 32; pB0 += 32; pB1 += 32;
        __syncthreads();
        short8 af[4], bfr[4];
#pragma unroll
        for (int i = 0; i < 4; i++)
            af[i] = *(const short8*)(As + (wm + i * 16 + l16) * 32 + ((quad ^ fx) * 8));
#pragma unroll
        for (int j = 0; j < 4; j++)
            bfr[j] = *(const short8*)(Bs + (wn + j * 16 + l16) * 32 + ((quad ^ fx) * 8));
#pragma unroll
        for (int i = 0; i < 4; i++)
#pragma unroll
            for (int j = 0; j < 4; j++)
                acc[i][j] = __builtin_amdgcn_mfma_f32_16x16x32_bf16(af[i], bfr[j], acc[i][j], 0, 0, 0);
        __syncthreads();
    }

    float* Yb = Y + (size_t)b * DIM * HW;
    float gamma = gammaPtr[0];
    const float* qb = qsrc + (size_t)b * DIM * HW;
#pragma unroll
    for (int j = 0; j < 4; j++) {
        int n = n0 + wn + j * 16 + l16;
        int pix = b * HW + n;
        float mn = mean[pix], rs = rstd[pix];
#pragma unroll
        for (int i = 0; i < 4; i++) {
            int mb = m0 + wm + i * 16 + quad * 4;
#pragma unroll
            for (int r = 0; r < 4; r++) {
                int m = mb + r;
                float qn = (qb[(size_t)m * HW + n] - mn) * rs * g[m] + beta[m];
                Yb[(size_t)m * HW + n] = gamma * acc[i][j][r] + qn;
            }
        }
    }
}

// ---------- kws[(b*512+c)][w] = sum_h |k[b][h*64+w][c]|, vectorized ---------
__global__ __launch_bounds__(256) void kws_kernel(const unsigned short* __restrict__ kbf,
                                                  float* __restrict__ kws)
{
    int blk = blockIdx.x;     // b*64 + w
    int b = blk >> 6, w = blk & 63;
    int tid = threadIdx.x;
    int c8 = tid & 63;        // channel group of 8
    int hq = tid >> 6;        // 4 h-slices of 16
    float a[8] = {};
    for (int hh = 0; hh < 16; hh++) {
        const unsigned short* row = kbf + ((size_t)(b * HW + (hq * 16 + hh) * 64 + w)) * 512 + c8 * 8;
        uint4 pk = *(const uint4*)row;
        const unsigned short* u = (const unsigned short*)&pk;
#pragma unroll
        for (int j = 0; j < 8; j++) a[j] += fabsf(bf2f(u[j]));
    }
    __shared__ float red[512 * 4];
#pragma unroll
    for (int j = 0; j < 8; j++) red[(c8 * 8 + j) * 4 + hq] = a[j];
    __syncthreads();
    if (tid < 256) {
        int c = tid;
        float v0 = red[c * 4] + red[c * 4 + 1] + red[c * 4 + 2] + red[c * 4 + 3];
        int c2 = tid + 256;
        float v1 = red[c2 * 4] + red[c2 * 4 + 1] + red[c2 * 4 + 2] + red[c2 * 4 + 3];
        kws[(size_t)(b * 512 + c) * 64 + w] = v0;
        kws[(size_t)(b * 512 + c2) * 64 + w] = v1;
    }
}

// ---------- scores + top-8 per bh ------------------------------------------
__global__ void score_topk(const float* __restrict__ qp, const float* __restrict__ khs,
                           const float* __restrict__ kws, int* __restrict__ idx_h, int* __restrict__ idx_w)
{
    int bh = blockIdx.x;
    int lane = threadIdx.x;
    float sr = 0.f, sc = 0.f;
    for (int c = 0; c < 64; c++) {
        float q = qp[bh * 64 + c];
        sr = fmaf(q, khs[(size_t)(bh * 64 + c) * 64 + lane], sr);
        sc = fmaf(q, kws[(size_t)(bh * 64 + c) * 64 + lane], sc);
    }
    float v = sr;
    for (int it = 0; it < 8; it++) {
        float bv = v; int bi = lane;
        for (int off = 1; off < 64; off <<= 1) {
            float ov = __shfl_xor(bv, off, 64);
            int oi = __shfl_xor(bi, off, 64);
            if (ov > bv || (ov == bv && oi < bi)) { bv = ov; bi = oi; }
        }
        if (lane == 0) idx_h[bh * 8 + it] = bi;
        if (lane == bi) v = -INFINITY;
    }
    v = sc;
    for (int it = 0; it < 8; it++) {
        float bv = v; int bi = lane;
        for (int off = 1; off < 64; off <<= 1) {
            float ov = __shfl_xor(bv, off, 64);
            int oi = __shfl_xor(bi, off, 64);
            if (ov > bv || (ov == bv && oi < bi)) { bv = ov; bi = oi; }
        }
        if (lane == 0) idx_w[bh * 8 + it] = bi;
        if (lane == bi) v = -INFINITY;
    }
}

// ---------- gather k rows; compute v at selected pixels ---------------------
__global__ void gather_kv(const unsigned short* __restrict__ kbf, const unsigned short* __restrict__ ctx_t,
                          const float* __restrict__ wv_g, const float* __restrict__ Av, const float* __restrict__ Cv,
                          const float* __restrict__ ctx_m, const float* __restrict__ ctx_r,
                          const int* __restrict__ idx_h, const int* __restrict__ idx_w,
                          unsigned short* __restrict__ kg, unsigned short* __restrict__ vgt)
{
    int blk = blockIdx.x;    // bh*64 + key
    int bh = blk >> 6, j = blk & 63;
    int h = idx_h[bh * 8 + (j >> 3)];
    int w = idx_w[bh * 8 + (j & 7)];
    int p = h * 64 + w;
    int b = bh >> 3, head = bh & 7;
    int d = threadIdx.x;     // 64
    kg[(size_t)blk * 64 + d] = kbf[(size_t)(b * HW + p) * 512 + head * 64 + d];
    __shared__ float cx[DIM];
    const unsigned short* crow = ctx_t + (size_t)(b * HW + p) * 512;
    short8 cv = ((const short8*)crow)[d];
#pragma unroll
    for (int u = 0; u < 8; u++) cx[d * 8 + u] = bf2f((unsigned short)cv[u]);
    __syncthreads();
    int o = head * 64 + d;
    const float* wrow = wv_g + (size_t)o * DIM;
    float acc = 0.f;
    for (int i = 0; i < DIM; i++) acc = fmaf(wrow[i], cx[i], acc);
    int pix = b * HW + p;
    float v = ctx_r[pix] * (acc - ctx_m[pix] * Av[o]) + Cv[o];
    vgt[((size_t)bh * 64 + d) * 64 + j] = f2bf(v);
}

// ---------- MFMA attention: S^T = K·Q^T, softmax over m, O^T = Vt·P ---------
#define PROW 72  // padded per-query LDS row stride (bf16)
__global__ __launch_bounds__(256) void attn_mfma(
    const unsigned short* __restrict__ qbf, const unsigned short* __restrict__ kg,
    const unsigned short* __restrict__ vgt, unsigned short* __restrict__ abuf)
{
    int bh = blockIdx.y;
    int b = bh >> 3, head = bh & 7;
    int tid = threadIdx.x;
    int lane = tid & 63, wave = tid >> 6;
    int g = lane >> 4, l16 = lane & 15;
    int p0 = blockIdx.x * 256 + wave * 64;

    __shared__ unsigned short Plds[4][64 * PROW];
    unsigned short* P = Plds[wave];

    const unsigned short* kgb = kg + (size_t)bh * 4096;
    const unsigned short* vtb = vgt + (size_t)bh * 4096;
    const unsigned short* qb = qbf + (size_t)(b * HW) * 512 + head * 64;

    short8 Qf[4][2];
#pragma unroll
    for (int j = 0; j < 4; j++)
#pragma unroll
        for (int t = 0; t < 2; t++)
            Qf[j][t] = *(const short8*)(qb + (size_t)(p0 + j * 16 + l16) * 512 + t * 32 + g * 8);

    f32x4 S[4][4];
#pragma unroll
    for (int i = 0; i < 4; i++)
#pragma unroll
        for (int j = 0; j < 4; j++) S[i][j] = (f32x4){0.f, 0.f, 0.f, 0.f};
#pragma unroll
    for (int t = 0; t < 2; t++) {
        short8 Kf[4];
#pragma unroll
        for (int i = 0; i < 4; i++)
            Kf[i] = *(const short8*)(kgb + (i * 16 + l16) * 64 + t * 32 + g * 8);
#pragma unroll
        for (int i = 0; i < 4; i++)
#pragma unroll
            for (int j = 0; j < 4; j++)
                S[i][j] = __builtin_amdgcn_mfma_f32_16x16x32_bf16(Kf[i], Qf[j][t], S[i][j], 0, 0, 0);
    }

    float inv[4];
#pragma unroll
    for (int j = 0; j < 4; j++) {
        float e[4][4];
        float s = 0.f;
#pragma unroll
        for (int i = 0; i < 4; i++)
#pragma unroll
            for (int r = 0; r < 4; r++) { e[i][r] = __expf(S[i][j][r]); s += e[i][r]; }
        s += __shfl_xor(s, 16, 64);
        s += __shfl_xor(s, 32, 64);
        inv[j] = 1.0f / s;
        int row = j * 16 + l16;
#pragma unroll
        for (int i = 0; i < 4; i++) {
            uint2 pk;
            pk.x = pack2(e[i][0], e[i][1]);
            pk.y = pack2(e[i][2], e[i][3]);
            *(uint2*)(P + row * PROW + i * 16 + g * 4) = pk;
        }
    }

    f32x4 O[4][4];
#pragma unroll
    for (int i = 0; i < 4; i++)
#pragma unroll
        for (int j = 0; j < 4; j++) O[i][j] = (f32x4){0.f, 0.f, 0.f, 0.f};
#pragma unroll
    for (int t = 0; t < 2; t++) {
        short8 Vf[4], Pf[4];
#pragma unroll
        for (int i = 0; i < 4; i++)
            Vf[i] = *(const short8*)(vtb + (i * 16 + l16) * 64 + t * 32 + g * 8);
#pragma unroll
        for (int j = 0; j < 4; j++)
            Pf[j] = *(const short8*)(P + (j * 16 + l16) * PROW + t * 32 + g * 8);
#pragma unroll
        for (int i = 0; i < 4; i++)
#pragma unroll
            for (int j = 0; j < 4; j++)
                O[i][j] = __builtin_amdgcn_mfma_f32_16x16x32_bf16(Vf[i], Pf[j], O[i][j], 0, 0, 0);
    }

    unsigned short* ob = abuf + (size_t)(b * HW) * 512 + head * 64;
#pragma unroll
    for (int j = 0; j < 4; j++) {
        int p = p0 + j * 16 + l16;
#pragma unroll
        for (int i = 0; i < 4; i++) {
            uint2 pk;
            pk.x = pack2(O[i][j][0] * inv[j], O[i][j][1] * inv[j]);
            pk.y = pack2(O[i][j][2] * inv[j], O[i][j][3] * inv[j]);
            *(uint2*)(ob + (size_t)p * 512 + i * 16 + g * 4) = pk;
        }
    }
}

extern "C" void kernel_launch(void* const* d_in, const int* in_sizes, int n_in,
                              void* d_out, int out_size, void* d_ws, size_t ws_size,
                              hipStream_t stream)
{
    (void)in_sizes; (void)n_in; (void)out_size;
    const float* ctx   = (const float*)d_in[0];
    const float* qs    = (const float*)d_in[1];
    const float* ctx_g = (const float*)d_in[2];
    const float* ctx_b = (const float*)d_in[3];
    const float* qs_g  = (const float*)d_in[4];
    const float* qs_b  = (const float*)d_in[5];
    const float* w_q   = (const float*)d_in[6];
    const float* w_kv  = (const float*)d_in[7];
    const float* w_out = (const float*)d_in[8];
    const float* gamma = (const float*)d_in[9];
    float* out = (float*)d_out;

    char* base = (char*)d_ws;
    // room for a dedicated kbf (needed to merge the two projection GEMMs)?
    bool sep = ws_size >= ((size_t)136 << 20);

    unsigned short* ctx_t = (unsigned short*)base;                 // 32 MB
    unsigned short* abuf  = ctx_t;                                 // alias after gather
    unsigned short* qs_t  = (unsigned short*)(base + ((size_t)32 << 20));
    unsigned short* qbf   = (unsigned short*)(base + ((size_t)64 << 20));
    unsigned short* kbf   = sep ? (unsigned short*)(base + ((size_t)96 << 20))
                                : qs_t;                            // fallback alias
    char* tail = base + (sep ? ((size_t)128 << 20) : ((size_t)96 << 20));
    unsigned short* wq_b = (unsigned short*)tail;                  // 262144 elems
    unsigned short* wk_b = wq_b + 262144;
    unsigned short* wo_b = wk_b + 262144;
    float* wv_g  = (float*)(wo_b + 262144);                        // 262144 f
    float* Avec  = wv_g + 262144;                                  // 1536
    float* Cvec  = Avec + 1536;
    float* ctx_m = Cvec + 1536;                                    // 32768 each
    float* ctx_r = ctx_m + 32768;
    float* qs_m  = ctx_r + 32768;
    float* qs_r  = qs_m + 32768;
    float* qp    = qs_r + 32768;                                   // 4096
    float* khs   = qp + 4096;                                      // 262144 (contiguous after qp)
    float* kws   = khs + 262144;                                   // 262144
    int*   idxh  = (int*)(kws + 262144);                           // 512
    int*   idxw  = idxh + 512;
    unsigned short* kg  = (unsigned short*)(idxw + 512);           // 262144 bf16
    unsigned short* vgt = kg + 262144;                             // 262144 bf16

    // fused: conv/transpose/stats + weight prep + qp/khs zeroing
    prep_conv<<<4161, 256, 0, stream>>>(ctx, qs, ctx_t, qs_t,
                                        ctx_m, ctx_r, qs_m, qs_r,
                                        w_q, w_kv, w_out, ctx_g, ctx_b, qs_g, qs_b,
                                        wq_b, wk_b, wo_b, wv_g, Avec, Cvec, qp);

    if (sep) {
        // both projection GEMMs in one dispatch (tails overlap)
        gemm_proj<<<dim3(32, 4, 16), 256, 0, stream>>>(
            wq_b, wk_b, qs_t, ctx_t, qbf, kbf,
            qs_m, qs_r, ctx_m, ctx_r, Avec, Cvec, qp, khs, 0);
    } else {
        // kbf aliases qs_t: q-proj (reads qs_t) must complete before k-proj
        gemm_proj<<<dim3(32, 4, 8), 256, 0, stream>>>(
            wq_b, wk_b, qs_t, ctx_t, qbf, kbf,
            qs_m, qs_r, ctx_m, ctx_r, Avec, Cvec, qp, khs, 0);
        gemm_proj<<<dim3(32, 4, 8), 256, 0, stream>>>(
            wq_b, wk_b, qs_t, ctx_t, qbf, kbf,
            qs_m, qs_r, ctx_m, ctx_r, Avec, Cvec, qp, khs, 8);
    }

    kws_kernel<<<512, 256, 0, stream>>>(kbf, kws);
    score_topk<<<64, 64, 0, stream>>>(qp, khs, kws, idxh, idxw);
    gather_kv<<<4096, 64, 0, stream>>>(kbf, ctx_t, wv_g, Avec + 1024, Cvec + 1024,
                                       ctx_m, ctx_r, idxh, idxw, kg, vgt);
    attn_mfma<<<dim3(16, 64), 256, 0, stream>>>(qbf, kg, vgt, abuf);
    gemm_out<<<dim3(32, 4, 8), 256, 0, stream>>>(wo_b, abuf, out, qs_m, qs_r,
                                                 qs, qs_g, qs_b, gamma);
}